// Round 8
// baseline (7945.861 us; speedup 1.0000x reference)
//
#include <hip/hip_runtime.h>
#include <math.h>

#define BB 64
#define NN 512
#define DD 32
#define LD2 36           // sA leading dim (pad col 32 holds per-column tk)
#define LDG 32           // sG leading dim (broadcast/bank-r reads only -> no pad needed)
#define JIT 1e-5f
#define TOLF 1e-4f
#define MAXIT 10

// lane-pull via LDS permute unit; addr = src_lane<<2
__device__ __forceinline__ float bpf(int addr, float v) {
    return __int_as_float(__builtin_amdgcn_ds_bpermute(addr, __float_as_int(v)));
}

__device__ __forceinline__ void wsync() {
    // wave-level LDS handoff (single-wave or per-wave-buffer use only)
    __asm__ volatile("s_waitcnt lgkmcnt(0)" ::: "memory");
}

// ---------------- one-sided (Hestenes) Jacobi, register-resident ----------------
// Lane = (col c = lane&31, half h = lane>>5) holds 16 rows of column c of W in a[16].
// XOR-cyclic sweeps: pair {c, c^m}, m=1..31. After convergence w_j = lam_j v_j.
__device__ __forceinline__ void jac1(float a[16], int aself, int a32, int c,
                                     int maxsweep, float thr) {
#pragma unroll 1
    for (int sweep = 0; sweep < maxsweep; ++sweep) {
        float maxrel = 0.f;
#pragma unroll 1
        for (int m = 1; m < 32; ++m) {
            int am = aself ^ (m << 2);
            float pa[16];
#pragma unroll
            for (int i = 0; i < 16; ++i) pa[i] = bpf(am, a[i]);
            float gs = 0.f, gc = 0.f;
#pragma unroll
            for (int i = 0; i < 16; ++i) {
                gs = fmaf(a[i], a[i], gs);
                gc = fmaf(a[i], pa[i], gc);
            }
            gs += bpf(a32, gs);
            gc += bpf(a32, gc);
            float gp = bpf(am, gs);
            bool isP = c < (c ^ m);
            float gpp = isP ? gs : gp;
            float gqq = isP ? gp : gs;
            float rel = gc * gc * __builtin_amdgcn_rcpf(gpp * gqq);
            maxrel = fmaxf(maxrel, rel);
            float tau = (gqq - gpp) * (0.5f * __builtin_amdgcn_rcpf(gc));
            float den = fabsf(tau) + __builtin_amdgcn_sqrtf(fmaf(tau, tau, 1.f));
            float tt  = copysignf(__builtin_amdgcn_rcpf(den), tau);
            tt = (rel > 1e-24f) ? tt : 0.f;
            float cs  = __builtin_amdgcn_rsqf(fmaf(tt, tt, 1.f));
            float sn  = tt * cs;
            float sg = isP ? -sn : sn;
#pragma unroll
            for (int i = 0; i < 16; ++i) a[i] = fmaf(sg, pa[i], cs * a[i]);
        }
#pragma unroll
        for (int sh = 1; sh <= 32; sh <<= 1)
            maxrel = fmaxf(maxrel, bpf(aself ^ (sh << 2), maxrel));
        if (maxrel < thr) break;
    }
}

// C = A * B (32x32, both stride LD2). Wave-synchronous, in-place safe (single wave).
__device__ __forceinline__ void mm32w(const float* A, const float* B, float* C, int lane) {
    int r = lane >> 1, cb = (lane & 1) << 4;
    float acc[16];
#pragma unroll
    for (int j = 0; j < 16; ++j) acc[j] = 0.0f;
    for (int k = 0; k < DD; ++k) {
        float a = A[r * LD2 + k];
        const float4* Br = (const float4*)(B + k * LD2 + cb);
        float4 b0 = Br[0], b1 = Br[1], b2 = Br[2], b3 = Br[3];
        acc[0]  = fmaf(a, b0.x, acc[0]);  acc[1]  = fmaf(a, b0.y, acc[1]);
        acc[2]  = fmaf(a, b0.z, acc[2]);  acc[3]  = fmaf(a, b0.w, acc[3]);
        acc[4]  = fmaf(a, b1.x, acc[4]);  acc[5]  = fmaf(a, b1.y, acc[5]);
        acc[6]  = fmaf(a, b1.z, acc[6]);  acc[7]  = fmaf(a, b1.w, acc[7]);
        acc[8]  = fmaf(a, b2.x, acc[8]);  acc[9]  = fmaf(a, b2.y, acc[9]);
        acc[10] = fmaf(a, b2.z, acc[10]); acc[11] = fmaf(a, b2.w, acc[11]);
        acc[12] = fmaf(a, b3.x, acc[12]); acc[13] = fmaf(a, b3.y, acc[13]);
        acc[14] = fmaf(a, b3.z, acc[14]); acc[15] = fmaf(a, b3.w, acc[15]);
    }
    wsync();
    float4* Cr = (float4*)(C + r * LD2 + cb);
    Cr[0] = make_float4(acc[0],  acc[1],  acc[2],  acc[3]);
    Cr[1] = make_float4(acc[4],  acc[5],  acc[6],  acc[7]);
    Cr[2] = make_float4(acc[8],  acc[9],  acc[10], acc[11]);
    Cr[3] = make_float4(acc[12], acc[13], acc[14], acc[15]);
    wsync();
}

// ---------------- setup ----------------

__global__ __launch_bounds__(256) void k0_zero(float* __restrict__ G, int* __restrict__ done,
                                               float* __restrict__ norm_acc, int* __restrict__ counter) {
    float4* Gb = (float4*)(G + blockIdx.x * 1024);
    Gb[threadIdx.x] = make_float4(0.f, 0.f, 0.f, 0.f);
    if (blockIdx.x == 0 && threadIdx.x == 0) { *done = 0; *norm_acc = 0.f; *counter = 0; }
}

__global__ __launch_bounds__(256) void k0_mean(const float* __restrict__ X, float* __restrict__ G) {
    int blk = blockIdx.x;
    int b = blk >> 3, chunk = blk & 7;
    int t = threadIdx.x;
    const float4* Xb = (const float4*)(X + ((size_t)(b * NN + chunk * 64)) * 1024);
    float4 acc = make_float4(0.f, 0.f, 0.f, 0.f);
    for (int n = 0; n < 64; ++n) {
        float4 v = Xb[n * 256 + t];
        acc.x += v.x; acc.y += v.y; acc.z += v.z; acc.w += v.w;
    }
    const float inv = 1.0f / NN;
    float* Gb = G + b * 1024 + t * 4;
    atomicAdd(Gb + 0, acc.x * inv);
    atomicAdd(Gb + 1, acc.y * inv);
    atomicAdd(Gb + 2, acc.z * inv);
    atomicAdd(Gb + 3, acc.w * inv);
}

// ---------------- k1: initial eigh(G0) -> Gs, Gis (once) ----------------

__global__ __launch_bounds__(64) void k1_init(const float* __restrict__ G,
                                              float* __restrict__ Gs, float* __restrict__ Gis) {
    int b = blockIdx.x, lane = threadIdx.x;
    int c = lane & 31, h = lane >> 5;
    int aself = lane << 2, a32 = aself ^ 128;
    int r = lane >> 1, cb = (lane & 1) << 4;
    __shared__ __align__(16) float sW[DD * LD2];
    __shared__ float sc1[DD], sc2[DD];

    float a[16];
    {
        const float4* Gc = (const float4*)(G + b * 1024 + c * 32 + 16 * h);
        float4 v0 = Gc[0], v1 = Gc[1], v2 = Gc[2], v3 = Gc[3];
        a[0]=v0.x; a[1]=v0.y; a[2]=v0.z; a[3]=v0.w;
        a[4]=v1.x; a[5]=v1.y; a[6]=v1.z; a[7]=v1.w;
        a[8]=v2.x; a[9]=v2.y; a[10]=v2.z; a[11]=v2.w;
        a[12]=v3.x; a[13]=v3.y; a[14]=v3.z; a[15]=v3.w;
#pragma unroll
        for (int i = 0; i < 16; ++i)
            if (16 * h + i == c) a[i] += JIT;   // _safe_eigh jitter
    }
    jac1(a, aself, a32, c, 10, 1e-12f);
    float gs2 = 0.f;
#pragma unroll
    for (int i = 0; i < 16; ++i) gs2 = fmaf(a[i], a[i], gs2);
    gs2 += bpf(a32, gs2);
    float l  = __builtin_amdgcn_sqrtf(gs2);
    float lc = fmaxf(l, JIT);
    float ig = __builtin_amdgcn_rcpf(gs2);
    float c1 = __builtin_amdgcn_sqrtf(lc) * ig;   // sqrt(clip(lam)) / lam^2
    float c2 = __builtin_amdgcn_rsqf(lc) * ig;    // 1/sqrt(clip(lam)) / lam^2
    {
        float4* wp = (float4*)&sW[c * LD2 + 16 * h];
        wp[0] = make_float4(a[0],  a[1],  a[2],  a[3]);
        wp[1] = make_float4(a[4],  a[5],  a[6],  a[7]);
        wp[2] = make_float4(a[8],  a[9],  a[10], a[11]);
        wp[3] = make_float4(a[12], a[13], a[14], a[15]);
        if (h == 0) { sc1[c] = c1; sc2[c] = c2; }
    }
    wsync();
    float a1[16], a2[16];
#pragma unroll
    for (int j = 0; j < 16; ++j) { a1[j] = 0.f; a2[j] = 0.f; }
    for (int k = 0; k < DD; ++k) {
        float wr = sW[k * LD2 + r];
        float t1 = wr * sc1[k], t2 = wr * sc2[k];
        const float4* Wc = (const float4*)&sW[k * LD2 + cb];
        float4 w0 = Wc[0], w1 = Wc[1], w2 = Wc[2], w3 = Wc[3];
        a1[0]+=t1*w0.x; a2[0]+=t2*w0.x;  a1[1]+=t1*w0.y; a2[1]+=t2*w0.y;
        a1[2]+=t1*w0.z; a2[2]+=t2*w0.z;  a1[3]+=t1*w0.w; a2[3]+=t2*w0.w;
        a1[4]+=t1*w1.x; a2[4]+=t2*w1.x;  a1[5]+=t1*w1.y; a2[5]+=t2*w1.y;
        a1[6]+=t1*w1.z; a2[6]+=t2*w1.z;  a1[7]+=t1*w1.w; a2[7]+=t2*w1.w;
        a1[8]+=t1*w2.x; a2[8]+=t2*w2.x;  a1[9]+=t1*w2.y; a2[9]+=t2*w2.y;
        a1[10]+=t1*w2.z; a2[10]+=t2*w2.z; a1[11]+=t1*w2.w; a2[11]+=t2*w2.w;
        a1[12]+=t1*w3.x; a2[12]+=t2*w3.x; a1[13]+=t1*w3.y; a2[13]+=t2*w3.y;
        a1[14]+=t1*w3.z; a2[14]+=t2*w3.z; a1[15]+=t1*w3.w; a2[15]+=t2*w3.w;
    }
    float4* Gsb  = (float4*)(Gs  + b * 1024 + lane * 16);
    float4* Gisb = (float4*)(Gis + b * 1024 + lane * 16);
#pragma unroll
    for (int j4 = 0; j4 < 4; ++j4) {
        Gsb[j4]  = make_float4(a1[4*j4], a1[4*j4+1], a1[4*j4+2], a1[4*j4+3]);
        Gisb[j4] = make_float4(a2[4*j4], a2[4*j4+1], a2[4*j4+2], a2[4*j4+3]);
    }
}

// ---------------- k2: hot kernel ----------------
// 512 blocks x 16 waves (1024 thr); LDS = 16*4608 (sA) + 4096 (sG) = 77824 B
// -> exactly 2 blocks/CU (155648 <= 163840, 8KB slack) = 32 waves/CU, single round.
// Block bx: b = bx>>3, grp = bx&7; wave wv handles 4 matrices n = grp*64 + wv*4 + nn.

__global__ __launch_bounds__(1024) void k2_log_acc(const float* __restrict__ X,
                                                   const float* __restrict__ Gis,
                                                   float* __restrict__ Part,
                                                   const int* __restrict__ done) {
    if (*done) return;
    int b = blockIdx.x >> 3, grp = blockIdx.x & 7;
    int wv = threadIdx.x >> 6, lane = threadIdx.x & 63;
    int c = lane & 31, h = lane >> 5;
    int aself = lane << 2, a32 = aself ^ 128;

    __shared__ __align__(16) float sG[DD * LDG];            // 4096 B
    __shared__ __align__(16) float sAall[16][DD * LD2];     // 73728 B
    float* sA = sAall[wv];

    if (threadIdx.x < 256)
        ((float4*)sG)[threadIdx.x] = ((const float4*)(Gis + b * 1024))[threadIdx.x];
    __syncthreads();

    int r = lane >> 1, cb = (lane & 1) << 4;
    float dacc[16];
#pragma unroll
    for (int j = 0; j < 16; ++j) dacc[j] = 0.f;

#pragma unroll 1
    for (int nn = 0; nn < 4; ++nn) {
        int n = grp * 64 + wv * 4 + nn;
        // ---- stage X[b,n] -> sA (row-major, stride LD2) ----
        {
            const float4* Xv = (const float4*)(X + ((size_t)(b * NN + n)) * 1024);
            float4 v0 = Xv[lane * 4 + 0], v1 = Xv[lane * 4 + 1];
            float4 v2 = Xv[lane * 4 + 2], v3 = Xv[lane * 4 + 3];
            wsync();   // all prior readers of sA done
            int e = lane * 16;
            float* d0 = &sA[(e >> 5) * LD2 + (e & 31)];
            *((float4*)d0)        = v0;
            *((float4*)(d0 + 4))  = v1;
            *((float4*)(d0 + 8))  = v2;
            *((float4*)(d0 + 12)) = v3;
            wsync();
        }
        // ---- T = Gis * X  (transposed A-operand: a = sG[k*LDG+r], bank-r conflict-free) ----
        {
            float acc[16];
#pragma unroll
            for (int j = 0; j < 16; ++j) acc[j] = 0.f;
            for (int k = 0; k < DD; ++k) {
                float a = sG[k * LDG + r];                 // Gis[k][r] = Gis[r][k]
                const float4* Br = (const float4*)(sA + k * LD2 + cb);
                float4 b0 = Br[0], b1 = Br[1], b2 = Br[2], b3 = Br[3];
                acc[0]  = fmaf(a, b0.x, acc[0]);  acc[1]  = fmaf(a, b0.y, acc[1]);
                acc[2]  = fmaf(a, b0.z, acc[2]);  acc[3]  = fmaf(a, b0.w, acc[3]);
                acc[4]  = fmaf(a, b1.x, acc[4]);  acc[5]  = fmaf(a, b1.y, acc[5]);
                acc[6]  = fmaf(a, b1.z, acc[6]);  acc[7]  = fmaf(a, b1.w, acc[7]);
                acc[8]  = fmaf(a, b2.x, acc[8]);  acc[9]  = fmaf(a, b2.y, acc[9]);
                acc[10] = fmaf(a, b2.z, acc[10]); acc[11] = fmaf(a, b2.w, acc[11]);
                acc[12] = fmaf(a, b3.x, acc[12]); acc[13] = fmaf(a, b3.y, acc[13]);
                acc[14] = fmaf(a, b3.z, acc[14]); acc[15] = fmaf(a, b3.w, acc[15]);
            }
            wsync();
            float4* Cr = (float4*)(sA + r * LD2 + cb);
            Cr[0] = make_float4(acc[0],  acc[1],  acc[2],  acc[3]);
            Cr[1] = make_float4(acc[4],  acc[5],  acc[6],  acc[7]);
            Cr[2] = make_float4(acc[8],  acc[9],  acc[10], acc[11]);
            Cr[3] = make_float4(acc[12], acc[13], acc[14], acc[15]);
            wsync();
        }
        // ---- A = T * Gis  (a = sA[r*LD2+k]; b = sG row k broadcast) ----
        {
            float acc[16];
#pragma unroll
            for (int j = 0; j < 16; ++j) acc[j] = 0.f;
            for (int k = 0; k < DD; ++k) {
                float a = sA[r * LD2 + k];
                const float4* Br = (const float4*)(sG + k * LDG + cb);
                float4 b0 = Br[0], b1 = Br[1], b2 = Br[2], b3 = Br[3];
                acc[0]  = fmaf(a, b0.x, acc[0]);  acc[1]  = fmaf(a, b0.y, acc[1]);
                acc[2]  = fmaf(a, b0.z, acc[2]);  acc[3]  = fmaf(a, b0.w, acc[3]);
                acc[4]  = fmaf(a, b1.x, acc[4]);  acc[5]  = fmaf(a, b1.y, acc[5]);
                acc[6]  = fmaf(a, b1.z, acc[6]);  acc[7]  = fmaf(a, b1.w, acc[7]);
                acc[8]  = fmaf(a, b2.x, acc[8]);  acc[9]  = fmaf(a, b2.y, acc[9]);
                acc[10] = fmaf(a, b2.z, acc[10]); acc[11] = fmaf(a, b2.w, acc[11]);
                acc[12] = fmaf(a, b3.x, acc[12]); acc[13] = fmaf(a, b3.y, acc[13]);
                acc[14] = fmaf(a, b3.z, acc[14]); acc[15] = fmaf(a, b3.w, acc[15]);
            }
            wsync();
            float4* Cr = (float4*)(sA + r * LD2 + cb);
            Cr[0] = make_float4(acc[0],  acc[1],  acc[2],  acc[3]);
            Cr[1] = make_float4(acc[4],  acc[5],  acc[6],  acc[7]);
            Cr[2] = make_float4(acc[8],  acc[9],  acc[10], acc[11]);
            Cr[3] = make_float4(acc[12], acc[13], acc[14], acc[15]);
            wsync();
        }
        // ---- extract column c (rows 16h..16h+15) with symmetrize + jitter ----
        float a[16];
        {
            const float4* cp = (const float4*)&sA[c * LD2 + 16 * h];
            float4 t0 = cp[0], t1 = cp[1], t2 = cp[2], t3 = cp[3];
            float tr[16] = { t0.x,t0.y,t0.z,t0.w, t1.x,t1.y,t1.z,t1.w,
                             t2.x,t2.y,t2.z,t2.w, t3.x,t3.y,t3.z,t3.w };
#pragma unroll
            for (int i = 0; i < 16; ++i) {
                int row = 16 * h + i;
                float v = 0.5f * (sA[row * LD2 + c] + tr[i]);
                if (row == c) v = tr[i] + JIT;
                a[i] = v;
            }
        }

        jac1(a, aself, a32, c, 8, 3e-10f);

        // ---- rebuild: dacc += W diag(log(lam)/lam^2) W^T ----
        {
            float gs2 = 0.f;
#pragma unroll
            for (int i = 0; i < 16; ++i) gs2 = fmaf(a[i], a[i], gs2);
            gs2 += bpf(a32, gs2);
            float gs2c = fmaxf(gs2, JIT * JIT);
            float tk = 0.5f * logf(gs2c) * __builtin_amdgcn_rcpf(gs2);
            wsync();   // prior readers of sA done
            float4* wp = (float4*)&sA[c * LD2 + 16 * h];
            wp[0] = make_float4(a[0],  a[1],  a[2],  a[3]);
            wp[1] = make_float4(a[4],  a[5],  a[6],  a[7]);
            wp[2] = make_float4(a[8],  a[9],  a[10], a[11]);
            wp[3] = make_float4(a[12], a[13], a[14], a[15]);
            if (h == 0) sA[c * LD2 + 32] = tk;          // tk in row padding
            wsync();
            for (int k = 0; k < DD; ++k) {
                float t1 = sA[k * LD2 + r] * sA[k * LD2 + 32];
                const float4* Wr = (const float4*)&sA[k * LD2 + cb];
                float4 w0 = Wr[0], w1 = Wr[1], w2 = Wr[2], w3 = Wr[3];
                dacc[0]  = fmaf(t1, w0.x, dacc[0]);  dacc[1]  = fmaf(t1, w0.y, dacc[1]);
                dacc[2]  = fmaf(t1, w0.z, dacc[2]);  dacc[3]  = fmaf(t1, w0.w, dacc[3]);
                dacc[4]  = fmaf(t1, w1.x, dacc[4]);  dacc[5]  = fmaf(t1, w1.y, dacc[5]);
                dacc[6]  = fmaf(t1, w1.z, dacc[6]);  dacc[7]  = fmaf(t1, w1.w, dacc[7]);
                dacc[8]  = fmaf(t1, w2.x, dacc[8]);  dacc[9]  = fmaf(t1, w2.y, dacc[9]);
                dacc[10] = fmaf(t1, w2.z, dacc[10]); dacc[11] = fmaf(t1, w2.w, dacc[11]);
                dacc[12] = fmaf(t1, w3.x, dacc[12]); dacc[13] = fmaf(t1, w3.y, dacc[13]);
                dacc[14] = fmaf(t1, w3.z, dacc[14]); dacc[15] = fmaf(t1, w3.w, dacc[15]);
            }
        }
    }
    wsync();

    // block reduction: dacc flat = lane*16+j
    {
        float4* fp = (float4*)&sA[lane * 16];
        fp[0] = make_float4(dacc[0],  dacc[1],  dacc[2],  dacc[3]);
        fp[1] = make_float4(dacc[4],  dacc[5],  dacc[6],  dacc[7]);
        fp[2] = make_float4(dacc[8],  dacc[9],  dacc[10], dacc[11]);
        fp[3] = make_float4(dacc[12], dacc[13], dacc[14], dacc[15]);
    }
    __syncthreads();
    if (threadIdx.x < 256) {
        int t = threadIdx.x;
        float4 s = ((float4*)sAall[0])[t];
#pragma unroll
        for (int w = 1; w < 16; ++w) {
            float4 v = ((float4*)sAall[w])[t];
            s.x += v.x; s.y += v.y; s.z += v.z; s.w += v.w;
        }
        ((float4*)(Part + (size_t)blockIdx.x * 1024))[t] = s;
    }
}

// ---------------- k31: fused G-update + eigh for next iteration ----------------

__global__ __launch_bounds__(64) void k31_update(float* __restrict__ G,
                                                 float* __restrict__ Gs,
                                                 float* __restrict__ Gis,
                                                 const float* __restrict__ Part,
                                                 float* __restrict__ norm_acc,
                                                 int* __restrict__ counter,
                                                 int* __restrict__ done) {
    if (*done) return;
    int b = blockIdx.x, lane = threadIdx.x;
    int c = lane & 31, h = lane >> 5;
    int aself = lane << 2, a32 = aself ^ 128;
    int r = lane >> 1, cb = (lane & 1) << 4;
    __shared__ __align__(16) float s0[DD * LD2], s1[DD * LD2], s2[DD * LD2];
    __shared__ float scg[DD], scs[DD], sci[DD];

    // Delta = sum of 8 partials / NN
    float d[16];
#pragma unroll
    for (int j = 0; j < 16; ++j) d[j] = 0.f;
#pragma unroll 1
    for (int g = 0; g < 8; ++g) {
        const float4* P = (const float4*)(Part + (size_t)(b * 8 + g) * 1024 + lane * 16);
        float4 p0 = P[0], p1 = P[1], p2 = P[2], p3 = P[3];
        d[0]+=p0.x; d[1]+=p0.y; d[2]+=p0.z; d[3]+=p0.w;
        d[4]+=p1.x; d[5]+=p1.y; d[6]+=p1.z; d[7]+=p1.w;
        d[8]+=p2.x; d[9]+=p2.y; d[10]+=p2.z; d[11]+=p2.w;
        d[12]+=p3.x; d[13]+=p3.y; d[14]+=p3.z; d[15]+=p3.w;
    }
    const float inv = 1.0f / NN;
    float sumsq = 0.f;
#pragma unroll
    for (int j = 0; j < 16; ++j) { d[j] *= inv; sumsq = fmaf(d[j], d[j], sumsq); }
#pragma unroll
    for (int sh = 1; sh <= 32; sh <<= 1) sumsq += bpf(aself ^ (sh << 2), sumsq);
    if (lane == 0) atomicAdd(norm_acc, sqrtf(sumsq));

    // Delta -> s0
    {
        float4* dp = (float4*)&s0[r * LD2 + cb];
        dp[0] = make_float4(d[0],  d[1],  d[2],  d[3]);
        dp[1] = make_float4(d[4],  d[5],  d[6],  d[7]);
        dp[2] = make_float4(d[8],  d[9],  d[10], d[11]);
        dp[3] = make_float4(d[12], d[13], d[14], d[15]);
    }
    wsync();

    // expm_taylor order 5
    float outr[16];
#pragma unroll
    for (int j = 0; j < 16; ++j)
        outr[j] = ((cb + j) == r ? 1.0f : 0.0f) + d[j];
    float fac = 1.0f;
#pragma unroll 1
    for (int i = 2; i <= 5; ++i) {
        fac *= (float)i;
        float acc[16];
#pragma unroll
        for (int j = 0; j < 16; ++j) acc[j] = 0.f;
        const float* Xp = (i == 2) ? s0 : s1;
        for (int k = 0; k < DD; ++k) {
            float av = Xp[r * LD2 + k];
            const float4* Br = (const float4*)&s0[k * LD2 + cb];
            float4 b0 = Br[0], b1 = Br[1], b2 = Br[2], b3 = Br[3];
            acc[0]+=av*b0.x; acc[1]+=av*b0.y; acc[2]+=av*b0.z; acc[3]+=av*b0.w;
            acc[4]+=av*b1.x; acc[5]+=av*b1.y; acc[6]+=av*b1.z; acc[7]+=av*b1.w;
            acc[8]+=av*b2.x; acc[9]+=av*b2.y; acc[10]+=av*b2.z; acc[11]+=av*b2.w;
            acc[12]+=av*b3.x; acc[13]+=av*b3.y; acc[14]+=av*b3.z; acc[15]+=av*b3.w;
        }
        float invf = 1.0f / fac;
#pragma unroll
        for (int j = 0; j < 16; ++j) outr[j] = fmaf(acc[j], invf, outr[j]);
        wsync();
        float4* dp = (float4*)&s1[r * LD2 + cb];
        dp[0] = make_float4(acc[0],  acc[1],  acc[2],  acc[3]);
        dp[1] = make_float4(acc[4],  acc[5],  acc[6],  acc[7]);
        dp[2] = make_float4(acc[8],  acc[9],  acc[10], acc[11]);
        dp[3] = make_float4(acc[12], acc[13], acc[14], acc[15]);
        wsync();
    }
    // E -> s0; Gs_old -> s1
    {
        float4* dp = (float4*)&s0[r * LD2 + cb];
        dp[0] = make_float4(outr[0],  outr[1],  outr[2],  outr[3]);
        dp[1] = make_float4(outr[4],  outr[5],  outr[6],  outr[7]);
        dp[2] = make_float4(outr[8],  outr[9],  outr[10], outr[11]);
        dp[3] = make_float4(outr[12], outr[13], outr[14], outr[15]);
        const float4* Gsb = (const float4*)(Gs + b * 1024);
#pragma unroll
        for (int j4 = 0; j4 < 4; ++j4) {
            float4 v = Gsb[lane * 4 + j4];
            int e = lane * 16 + j4 * 4;
            *((float4*)&s1[(e >> 5) * LD2 + (e & 31)]) = v;
        }
    }
    wsync();
    mm32w(s1, s0, s2, lane);   // T = Gs * E
    mm32w(s2, s1, s0, lane);   // M = T * Gs

    // enforce_spd eigh: extract col with symmetrize + jitter
    float a[16];
#pragma unroll
    for (int i = 0; i < 16; ++i) {
        int row = 16 * h + i;
        float own = s0[c * LD2 + row];
        float v = 0.5f * (s0[row * LD2 + c] + own);
        if (row == c) v = own + JIT;
        a[i] = v;
    }
    jac1(a, aself, a32, c, 10, 1e-12f);
    float gs2 = 0.f;
#pragma unroll
    for (int i = 0; i < 16; ++i) gs2 = fmaf(a[i], a[i], gs2);
    gs2 += bpf(a32, gs2);
    float l = __builtin_amdgcn_sqrtf(gs2);
    float clipl = fmaxf(l, JIT);
    float ig = __builtin_amdgcn_rcpf(gs2);
    float tg = clipl * ig;                      // G:   clip(lam)/lam^2
    float sh = clipl + JIT;                     // next eigh's vals (same eigvecs)
    float ts = __builtin_amdgcn_sqrtf(sh) * ig; // Gs:  sqrt(clip+JIT)/lam^2
    float ti = __builtin_amdgcn_rsqf(sh) * ig;  // Gis: rsqrt(clip+JIT)/lam^2
    wsync();
    {
        float4* wp = (float4*)&s1[c * LD2 + 16 * h];
        wp[0] = make_float4(a[0],  a[1],  a[2],  a[3]);
        wp[1] = make_float4(a[4],  a[5],  a[6],  a[7]);
        wp[2] = make_float4(a[8],  a[9],  a[10], a[11]);
        wp[3] = make_float4(a[12], a[13], a[14], a[15]);
        if (h == 0) { scg[c] = tg; scs[c] = ts; sci[c] = ti; }
    }
    wsync();
    float gg[16], gsv[16], giv[16];
#pragma unroll
    for (int j = 0; j < 16; ++j) { gg[j] = 0.f; gsv[j] = 0.f; giv[j] = 0.f; }
    for (int k = 0; k < DD; ++k) {
        float wr = s1[k * LD2 + r];
        float cg = wr * scg[k], cs2 = wr * scs[k], ci = wr * sci[k];
        const float4* Wc = (const float4*)&s1[k * LD2 + cb];
        float4 w0 = Wc[0], w1 = Wc[1], w2 = Wc[2], w3 = Wc[3];
        gg[0]+=cg*w0.x; gsv[0]+=cs2*w0.x; giv[0]+=ci*w0.x;
        gg[1]+=cg*w0.y; gsv[1]+=cs2*w0.y; giv[1]+=ci*w0.y;
        gg[2]+=cg*w0.z; gsv[2]+=cs2*w0.z; giv[2]+=ci*w0.z;
        gg[3]+=cg*w0.w; gsv[3]+=cs2*w0.w; giv[3]+=ci*w0.w;
        gg[4]+=cg*w1.x; gsv[4]+=cs2*w1.x; giv[4]+=ci*w1.x;
        gg[5]+=cg*w1.y; gsv[5]+=cs2*w1.y; giv[5]+=ci*w1.y;
        gg[6]+=cg*w1.z; gsv[6]+=cs2*w1.z; giv[6]+=ci*w1.z;
        gg[7]+=cg*w1.w; gsv[7]+=cs2*w1.w; giv[7]+=ci*w1.w;
        gg[8]+=cg*w2.x; gsv[8]+=cs2*w2.x; giv[8]+=ci*w2.x;
        gg[9]+=cg*w2.y; gsv[9]+=cs2*w2.y; giv[9]+=ci*w2.y;
        gg[10]+=cg*w2.z; gsv[10]+=cs2*w2.z; giv[10]+=ci*w2.z;
        gg[11]+=cg*w2.w; gsv[11]+=cs2*w2.w; giv[11]+=ci*w2.w;
        gg[12]+=cg*w3.x; gsv[12]+=cs2*w3.x; giv[12]+=ci*w3.x;
        gg[13]+=cg*w3.y; gsv[13]+=cs2*w3.y; giv[13]+=ci*w3.y;
        gg[14]+=cg*w3.z; gsv[14]+=cs2*w3.z; giv[14]+=ci*w3.z;
        gg[15]+=cg*w3.w; gsv[15]+=cs2*w3.w; giv[15]+=ci*w3.w;
    }
    float4* Gb   = (float4*)(G   + b * 1024 + lane * 16);
    float4* Gsb  = (float4*)(Gs  + b * 1024 + lane * 16);
    float4* Gib  = (float4*)(Gis + b * 1024 + lane * 16);
#pragma unroll
    for (int j4 = 0; j4 < 4; ++j4) {
        Gb[j4]  = make_float4(gg[4*j4],  gg[4*j4+1],  gg[4*j4+2],  gg[4*j4+3]);
        Gsb[j4] = make_float4(gsv[4*j4], gsv[4*j4+1], gsv[4*j4+2], gsv[4*j4+3]);
        Gib[j4] = make_float4(giv[4*j4], giv[4*j4+1], giv[4*j4+2], giv[4*j4+3]);
    }

    // convergence check by last-finishing block
    __threadfence();
    if (lane == 0) {
        int ret = atomicAdd(counter, 1);
        if (ret == BB - 1) {
            float nm = atomicAdd(norm_acc, 0.f);
            if (nm * (1.0f / BB) < TOLF) *done = 1;
            *norm_acc = 0.f;
            *counter = 0;
            __threadfence();
        }
    }
}

__global__ __launch_bounds__(256) void k5_out(const float* __restrict__ G, float* __restrict__ out) {
    int i = blockIdx.x * 256 + threadIdx.x;
    out[i] = G[i];
}

extern "C" void kernel_launch(void* const* d_in, const int* in_sizes, int n_in,
                              void* d_out, int out_size, void* d_ws, size_t ws_size,
                              hipStream_t stream) {
    const float* X = (const float*)d_in[0];
    float* ws = (float*)d_ws;
    float* G     = ws;                        // 65536
    float* Gs    = ws + 65536;                // 65536
    float* Gis   = ws + 2 * 65536;            // 65536
    float* Part  = ws + 3 * 65536;            // 512 blocks * 1024 = 524288
    float* norm_acc = ws + 3 * 65536 + 524288;
    int*   counter  = (int*)(norm_acc + 1);
    int*   done     = (int*)(norm_acc + 2);

    k0_zero<<<64, 256, 0, stream>>>(G, done, norm_acc, counter);
    k0_mean<<<512, 256, 0, stream>>>(X, G);
    k1_init<<<64, 64, 0, stream>>>(G, Gs, Gis);
    for (int it = 0; it < MAXIT; ++it) {
        k2_log_acc<<<512, 1024, 0, stream>>>(X, Gis, Part, done);
        k31_update<<<64, 64, 0, stream>>>(G, Gs, Gis, Part, norm_acc, counter, done);
    }
    k5_out<<<256, 256, 0, stream>>>(G, (float*)d_out);
}

// Round 9
// 5319.580 us; speedup vs baseline: 1.4937x; 1.4937x over previous
//
#include <hip/hip_runtime.h>
#include <math.h>

#define BB 64
#define NN 512
#define DD 32
#define LD2 36           // sA leading dim (pad col 32 holds per-column tk)
#define LDG 32           // sG leading dim (broadcast/bank-r reads only)
#define JIT 1e-5f
#define TOLF 1e-4f
#define MAXIT 10

// lane-pull via LDS permute unit; addr = src_lane<<2
__device__ __forceinline__ float bpf(int addr, float v) {
    return __int_as_float(__builtin_amdgcn_ds_bpermute(addr, __float_as_int(v)));
}

__device__ __forceinline__ void wsync() {
    // wave-level LDS handoff (single-wave or per-wave-buffer use only)
    __asm__ volatile("s_waitcnt lgkmcnt(0)" ::: "memory");
}

// ---------------- one-sided (Hestenes) Jacobi, register-resident ----------------
__device__ __forceinline__ void jac1(float a[16], int aself, int a32, int c,
                                     int maxsweep, float thr) {
#pragma unroll 1
    for (int sweep = 0; sweep < maxsweep; ++sweep) {
        float maxrel = 0.f;
#pragma unroll 1
        for (int m = 1; m < 32; ++m) {
            int am = aself ^ (m << 2);
            float pa[16];
#pragma unroll
            for (int i = 0; i < 16; ++i) pa[i] = bpf(am, a[i]);
            float gs = 0.f, gc = 0.f;
#pragma unroll
            for (int i = 0; i < 16; ++i) {
                gs = fmaf(a[i], a[i], gs);
                gc = fmaf(a[i], pa[i], gc);
            }
            gs += bpf(a32, gs);
            gc += bpf(a32, gc);
            float gp = bpf(am, gs);
            bool isP = c < (c ^ m);
            float gpp = isP ? gs : gp;
            float gqq = isP ? gp : gs;
            float rel = gc * gc * __builtin_amdgcn_rcpf(gpp * gqq);
            maxrel = fmaxf(maxrel, rel);
            float tau = (gqq - gpp) * (0.5f * __builtin_amdgcn_rcpf(gc));
            float den = fabsf(tau) + __builtin_amdgcn_sqrtf(fmaf(tau, tau, 1.f));
            float tt  = copysignf(__builtin_amdgcn_rcpf(den), tau);
            tt = (rel > 1e-24f) ? tt : 0.f;
            float cs  = __builtin_amdgcn_rsqf(fmaf(tt, tt, 1.f));
            float sn  = tt * cs;
            float sg = isP ? -sn : sn;
#pragma unroll
            for (int i = 0; i < 16; ++i) a[i] = fmaf(sg, pa[i], cs * a[i]);
        }
#pragma unroll
        for (int sh = 1; sh <= 32; sh <<= 1)
            maxrel = fmaxf(maxrel, bpf(aself ^ (sh << 2), maxrel));
        if (maxrel < thr) break;
    }
}

// C = A * B (32x32, both stride LD2). Wave-synchronous, in-place safe (single wave).
__device__ __forceinline__ void mm32w(const float* A, const float* B, float* C, int lane) {
    int r = lane >> 1, cb = (lane & 1) << 4;
    float acc[16];
#pragma unroll
    for (int j = 0; j < 16; ++j) acc[j] = 0.0f;
    for (int k = 0; k < DD; ++k) {
        float a = A[r * LD2 + k];
        const float4* Br = (const float4*)(B + k * LD2 + cb);
        float4 b0 = Br[0], b1 = Br[1], b2 = Br[2], b3 = Br[3];
        acc[0]  = fmaf(a, b0.x, acc[0]);  acc[1]  = fmaf(a, b0.y, acc[1]);
        acc[2]  = fmaf(a, b0.z, acc[2]);  acc[3]  = fmaf(a, b0.w, acc[3]);
        acc[4]  = fmaf(a, b1.x, acc[4]);  acc[5]  = fmaf(a, b1.y, acc[5]);
        acc[6]  = fmaf(a, b1.z, acc[6]);  acc[7]  = fmaf(a, b1.w, acc[7]);
        acc[8]  = fmaf(a, b2.x, acc[8]);  acc[9]  = fmaf(a, b2.y, acc[9]);
        acc[10] = fmaf(a, b2.z, acc[10]); acc[11] = fmaf(a, b2.w, acc[11]);
        acc[12] = fmaf(a, b3.x, acc[12]); acc[13] = fmaf(a, b3.y, acc[13]);
        acc[14] = fmaf(a, b3.z, acc[14]); acc[15] = fmaf(a, b3.w, acc[15]);
    }
    wsync();
    float4* Cr = (float4*)(C + r * LD2 + cb);
    Cr[0] = make_float4(acc[0],  acc[1],  acc[2],  acc[3]);
    Cr[1] = make_float4(acc[4],  acc[5],  acc[6],  acc[7]);
    Cr[2] = make_float4(acc[8],  acc[9],  acc[10], acc[11]);
    Cr[3] = make_float4(acc[12], acc[13], acc[14], acc[15]);
    wsync();
}

// ---------------- setup ----------------

__global__ __launch_bounds__(256) void k0_zero(float* __restrict__ G, int* __restrict__ done,
                                               float* __restrict__ norm_acc, int* __restrict__ counter) {
    float4* Gb = (float4*)(G + blockIdx.x * 1024);
    Gb[threadIdx.x] = make_float4(0.f, 0.f, 0.f, 0.f);
    if (blockIdx.x == 0 && threadIdx.x == 0) { *done = 0; *norm_acc = 0.f; *counter = 0; }
}

__global__ __launch_bounds__(256) void k0_mean(const float* __restrict__ X, float* __restrict__ G) {
    int blk = blockIdx.x;
    int b = blk >> 3, chunk = blk & 7;
    int t = threadIdx.x;
    const float4* Xb = (const float4*)(X + ((size_t)(b * NN + chunk * 64)) * 1024);
    float4 acc = make_float4(0.f, 0.f, 0.f, 0.f);
    for (int n = 0; n < 64; ++n) {
        float4 v = Xb[n * 256 + t];
        acc.x += v.x; acc.y += v.y; acc.z += v.z; acc.w += v.w;
    }
    const float inv = 1.0f / NN;
    float* Gb = G + b * 1024 + t * 4;
    atomicAdd(Gb + 0, acc.x * inv);
    atomicAdd(Gb + 1, acc.y * inv);
    atomicAdd(Gb + 2, acc.z * inv);
    atomicAdd(Gb + 3, acc.w * inv);
}

// ---------------- k1: initial eigh(G0) -> Gs, Gis (once) ----------------

__global__ __launch_bounds__(64) void k1_init(const float* __restrict__ G,
                                              float* __restrict__ Gs, float* __restrict__ Gis) {
    int b = blockIdx.x, lane = threadIdx.x;
    int c = lane & 31, h = lane >> 5;
    int aself = lane << 2, a32 = aself ^ 128;
    int r = lane >> 1, cb = (lane & 1) << 4;
    __shared__ __align__(16) float sW[DD * LD2];
    __shared__ float sc1[DD], sc2[DD];

    float a[16];
    {
        const float4* Gc = (const float4*)(G + b * 1024 + c * 32 + 16 * h);
        float4 v0 = Gc[0], v1 = Gc[1], v2 = Gc[2], v3 = Gc[3];
        a[0]=v0.x; a[1]=v0.y; a[2]=v0.z; a[3]=v0.w;
        a[4]=v1.x; a[5]=v1.y; a[6]=v1.z; a[7]=v1.w;
        a[8]=v2.x; a[9]=v2.y; a[10]=v2.z; a[11]=v2.w;
        a[12]=v3.x; a[13]=v3.y; a[14]=v3.z; a[15]=v3.w;
#pragma unroll
        for (int i = 0; i < 16; ++i)
            if (16 * h + i == c) a[i] += JIT;   // _safe_eigh jitter
    }
    jac1(a, aself, a32, c, 10, 1e-12f);
    float gs2 = 0.f;
#pragma unroll
    for (int i = 0; i < 16; ++i) gs2 = fmaf(a[i], a[i], gs2);
    gs2 += bpf(a32, gs2);
    float l  = __builtin_amdgcn_sqrtf(gs2);
    float lc = fmaxf(l, JIT);
    float ig = __builtin_amdgcn_rcpf(gs2);
    float c1 = __builtin_amdgcn_sqrtf(lc) * ig;   // sqrt(clip(lam)) / lam^2
    float c2 = __builtin_amdgcn_rsqf(lc) * ig;    // 1/sqrt(clip(lam)) / lam^2
    {
        float4* wp = (float4*)&sW[c * LD2 + 16 * h];
        wp[0] = make_float4(a[0],  a[1],  a[2],  a[3]);
        wp[1] = make_float4(a[4],  a[5],  a[6],  a[7]);
        wp[2] = make_float4(a[8],  a[9],  a[10], a[11]);
        wp[3] = make_float4(a[12], a[13], a[14], a[15]);
        if (h == 0) { sc1[c] = c1; sc2[c] = c2; }
    }
    wsync();
    float a1[16], a2[16];
#pragma unroll
    for (int j = 0; j < 16; ++j) { a1[j] = 0.f; a2[j] = 0.f; }
    for (int k = 0; k < DD; ++k) {
        float wr = sW[k * LD2 + r];
        float t1 = wr * sc1[k], t2 = wr * sc2[k];
        const float4* Wc = (const float4*)&sW[k * LD2 + cb];
        float4 w0 = Wc[0], w1 = Wc[1], w2 = Wc[2], w3 = Wc[3];
        a1[0]+=t1*w0.x; a2[0]+=t2*w0.x;  a1[1]+=t1*w0.y; a2[1]+=t2*w0.y;
        a1[2]+=t1*w0.z; a2[2]+=t2*w0.z;  a1[3]+=t1*w0.w; a2[3]+=t2*w0.w;
        a1[4]+=t1*w1.x; a2[4]+=t2*w1.x;  a1[5]+=t1*w1.y; a2[5]+=t2*w1.y;
        a1[6]+=t1*w1.z; a2[6]+=t2*w1.z;  a1[7]+=t1*w1.w; a2[7]+=t2*w1.w;
        a1[8]+=t1*w2.x; a2[8]+=t2*w2.x;  a1[9]+=t1*w2.y; a2[9]+=t2*w2.y;
        a1[10]+=t1*w2.z; a2[10]+=t2*w2.z; a1[11]+=t1*w2.w; a2[11]+=t2*w2.w;
        a1[12]+=t1*w3.x; a2[12]+=t2*w3.x; a1[13]+=t1*w3.y; a2[13]+=t2*w3.y;
        a1[14]+=t1*w3.z; a2[14]+=t2*w3.z; a1[15]+=t1*w3.w; a2[15]+=t2*w3.w;
    }
    float4* Gsb  = (float4*)(Gs  + b * 1024 + lane * 16);
    float4* Gisb = (float4*)(Gis + b * 1024 + lane * 16);
#pragma unroll
    for (int j4 = 0; j4 < 4; ++j4) {
        Gsb[j4]  = make_float4(a1[4*j4], a1[4*j4+1], a1[4*j4+2], a1[4*j4+3]);
        Gisb[j4] = make_float4(a2[4*j4], a2[4*j4+1], a2[4*j4+2], a2[4*j4+3]);
    }
}

// ---------------- k2: hot kernel ----------------
// 1024 blocks x 8 waves; wave handles 4 matrices. it>0: warm-start Jacobi with V
// from the previous outer iteration (Vbuf, 128 MB in d_ws). it==0 (or no Vbuf
// capacity): cold start from columns of A.

__global__ __launch_bounds__(512) void k2_log_acc(const float* __restrict__ X,
                                                  const float* __restrict__ Gis,
                                                  float* __restrict__ Part,
                                                  const int* __restrict__ done,
                                                  float* __restrict__ Vbuf,
                                                  int it) {
    if (*done) return;
    int b = blockIdx.x >> 4, grp = blockIdx.x & 15;
    int wv = threadIdx.x >> 6, lane = threadIdx.x & 63;
    int c = lane & 31, h = lane >> 5;
    int aself = lane << 2, a32 = aself ^ 128;

    __shared__ __align__(16) float sG[DD * LDG];           // 4096 B
    __shared__ __align__(16) float sAall[8][DD * LD2];     // 36864 B
    float* sA = sAall[wv];

    if (threadIdx.x < 256)
        ((float4*)sG)[threadIdx.x] = ((const float4*)(Gis + b * 1024))[threadIdx.x];
    __syncthreads();

    int r = lane >> 1, cb = (lane & 1) << 4;
    float dacc[16];
#pragma unroll
    for (int j = 0; j < 16; ++j) dacc[j] = 0.f;

#pragma unroll 1
    for (int nn = 0; nn < 4; ++nn) {
        int n = grp * 32 + wv * 4 + nn;
        // ---- stage X[b,n] -> sA ----
        {
            const float4* Xv = (const float4*)(X + ((size_t)(b * NN + n)) * 1024);
            float4 v0 = Xv[lane * 4 + 0], v1 = Xv[lane * 4 + 1];
            float4 v2 = Xv[lane * 4 + 2], v3 = Xv[lane * 4 + 3];
            wsync();   // all prior readers of sA done
            int e = lane * 16;
            float* d0 = &sA[(e >> 5) * LD2 + (e & 31)];
            *((float4*)d0)        = v0;
            *((float4*)(d0 + 4))  = v1;
            *((float4*)(d0 + 8))  = v2;
            *((float4*)(d0 + 12)) = v3;
            wsync();
        }
        // ---- T = Gis * X (A-operand transposed read from sG: conflict-free) ----
        {
            float acc[16];
#pragma unroll
            for (int j = 0; j < 16; ++j) acc[j] = 0.f;
            for (int k = 0; k < DD; ++k) {
                float a = sG[k * LDG + r];
                const float4* Br = (const float4*)(sA + k * LD2 + cb);
                float4 b0 = Br[0], b1 = Br[1], b2 = Br[2], b3 = Br[3];
                acc[0]  = fmaf(a, b0.x, acc[0]);  acc[1]  = fmaf(a, b0.y, acc[1]);
                acc[2]  = fmaf(a, b0.z, acc[2]);  acc[3]  = fmaf(a, b0.w, acc[3]);
                acc[4]  = fmaf(a, b1.x, acc[4]);  acc[5]  = fmaf(a, b1.y, acc[5]);
                acc[6]  = fmaf(a, b1.z, acc[6]);  acc[7]  = fmaf(a, b1.w, acc[7]);
                acc[8]  = fmaf(a, b2.x, acc[8]);  acc[9]  = fmaf(a, b2.y, acc[9]);
                acc[10] = fmaf(a, b2.z, acc[10]); acc[11] = fmaf(a, b2.w, acc[11]);
                acc[12] = fmaf(a, b3.x, acc[12]); acc[13] = fmaf(a, b3.y, acc[13]);
                acc[14] = fmaf(a, b3.z, acc[14]); acc[15] = fmaf(a, b3.w, acc[15]);
            }
            wsync();
            float4* Cr = (float4*)(sA + r * LD2 + cb);
            Cr[0] = make_float4(acc[0],  acc[1],  acc[2],  acc[3]);
            Cr[1] = make_float4(acc[4],  acc[5],  acc[6],  acc[7]);
            Cr[2] = make_float4(acc[8],  acc[9],  acc[10], acc[11]);
            Cr[3] = make_float4(acc[12], acc[13], acc[14], acc[15]);
            wsync();
        }
        // ---- A = T * Gis ----
        {
            float acc[16];
#pragma unroll
            for (int j = 0; j < 16; ++j) acc[j] = 0.f;
            for (int k = 0; k < DD; ++k) {
                float a = sA[r * LD2 + k];
                const float4* Br = (const float4*)(sG + k * LDG + cb);
                float4 b0 = Br[0], b1 = Br[1], b2 = Br[2], b3 = Br[3];
                acc[0]  = fmaf(a, b0.x, acc[0]);  acc[1]  = fmaf(a, b0.y, acc[1]);
                acc[2]  = fmaf(a, b0.z, acc[2]);  acc[3]  = fmaf(a, b0.w, acc[3]);
                acc[4]  = fmaf(a, b1.x, acc[4]);  acc[5]  = fmaf(a, b1.y, acc[5]);
                acc[6]  = fmaf(a, b1.z, acc[6]);  acc[7]  = fmaf(a, b1.w, acc[7]);
                acc[8]  = fmaf(a, b2.x, acc[8]);  acc[9]  = fmaf(a, b2.y, acc[9]);
                acc[10] = fmaf(a, b2.z, acc[10]); acc[11] = fmaf(a, b2.w, acc[11]);
                acc[12] = fmaf(a, b3.x, acc[12]); acc[13] = fmaf(a, b3.y, acc[13]);
                acc[14] = fmaf(a, b3.z, acc[14]); acc[15] = fmaf(a, b3.w, acc[15]);
            }
            wsync();
            float4* Cr = (float4*)(sA + r * LD2 + cb);
            Cr[0] = make_float4(acc[0],  acc[1],  acc[2],  acc[3]);
            Cr[1] = make_float4(acc[4],  acc[5],  acc[6],  acc[7]);
            Cr[2] = make_float4(acc[8],  acc[9],  acc[10], acc[11]);
            Cr[3] = make_float4(acc[12], acc[13], acc[14], acc[15]);
            wsync();
        }
        // ---- initial W columns: cold (A cols, symmetrized) or warm (A * V_prev) ----
        float a[16];
        if (it == 0) {
            const float4* cp = (const float4*)&sA[c * LD2 + 16 * h];
            float4 t0 = cp[0], t1 = cp[1], t2 = cp[2], t3 = cp[3];
            float tr[16] = { t0.x,t0.y,t0.z,t0.w, t1.x,t1.y,t1.z,t1.w,
                             t2.x,t2.y,t2.z,t2.w, t3.x,t3.y,t3.z,t3.w };
#pragma unroll
            for (int i = 0; i < 16; ++i) {
                int row = 16 * h + i;
                float v = 0.5f * (sA[row * LD2 + c] + tr[i]);
                if (row == c) v = tr[i] + JIT;
                a[i] = v;
            }
        } else {
            // w_c = (A + JIT I) * vhat_prev_c ; vhat in registers, A rows broadcast from LDS
            float v[32];
            {
                const float4* Vp = (const float4*)(Vbuf + ((size_t)(b * NN + n)) * 1024 + c * 32);
#pragma unroll
                for (int j4 = 0; j4 < 8; ++j4) {
                    float4 t = Vp[j4];
                    v[4*j4] = t.x; v[4*j4+1] = t.y; v[4*j4+2] = t.z; v[4*j4+3] = t.w;
                }
            }
#pragma unroll
            for (int i = 0; i < 16; ++i) {
                const float4* Ar = (const float4*)&sA[(16 * h + i) * LD2];
                float s = 0.f;
#pragma unroll
                for (int j4 = 0; j4 < 8; ++j4) {
                    float4 q = Ar[j4];
                    s = fmaf(q.x, v[4*j4],   s);
                    s = fmaf(q.y, v[4*j4+1], s);
                    s = fmaf(q.z, v[4*j4+2], s);
                    s = fmaf(q.w, v[4*j4+3], s);
                }
                a[i] = fmaf(JIT, v[16 * h + i], s);
            }
        }

        jac1(a, aself, a32, c, 8, 3e-10f);

        // ---- eigen extraction + V store + rebuild ----
        {
            float gs2 = 0.f;
#pragma unroll
            for (int i = 0; i < 16; ++i) gs2 = fmaf(a[i], a[i], gs2);
            gs2 += bpf(a32, gs2);
            float gs2c = fmaxf(gs2, JIT * JIT);
            float tk = 0.5f * logf(gs2c) * __builtin_amdgcn_rcpf(gs2);
            if (Vbuf) {   // store normalized eigenvectors for next iteration's warm start
                float inl = __builtin_amdgcn_rsqf(gs2);
                float4* Vp = (float4*)(Vbuf + ((size_t)(b * NN + n)) * 1024 + c * 32 + 16 * h);
                Vp[0] = make_float4(a[0]*inl,  a[1]*inl,  a[2]*inl,  a[3]*inl);
                Vp[1] = make_float4(a[4]*inl,  a[5]*inl,  a[6]*inl,  a[7]*inl);
                Vp[2] = make_float4(a[8]*inl,  a[9]*inl,  a[10]*inl, a[11]*inl);
                Vp[3] = make_float4(a[12]*inl, a[13]*inl, a[14]*inl, a[15]*inl);
            }
            wsync();   // prior readers of sA done
            float4* wp = (float4*)&sA[c * LD2 + 16 * h];
            wp[0] = make_float4(a[0],  a[1],  a[2],  a[3]);
            wp[1] = make_float4(a[4],  a[5],  a[6],  a[7]);
            wp[2] = make_float4(a[8],  a[9],  a[10], a[11]);
            wp[3] = make_float4(a[12], a[13], a[14], a[15]);
            if (h == 0) sA[c * LD2 + 32] = tk;          // tk in row padding
            wsync();
            for (int k = 0; k < DD; ++k) {
                float t1 = sA[k * LD2 + r] * sA[k * LD2 + 32];
                const float4* Wr = (const float4*)&sA[k * LD2 + cb];
                float4 w0 = Wr[0], w1 = Wr[1], w2 = Wr[2], w3 = Wr[3];
                dacc[0]  = fmaf(t1, w0.x, dacc[0]);  dacc[1]  = fmaf(t1, w0.y, dacc[1]);
                dacc[2]  = fmaf(t1, w0.z, dacc[2]);  dacc[3]  = fmaf(t1, w0.w, dacc[3]);
                dacc[4]  = fmaf(t1, w1.x, dacc[4]);  dacc[5]  = fmaf(t1, w1.y, dacc[5]);
                dacc[6]  = fmaf(t1, w1.z, dacc[6]);  dacc[7]  = fmaf(t1, w1.w, dacc[7]);
                dacc[8]  = fmaf(t1, w2.x, dacc[8]);  dacc[9]  = fmaf(t1, w2.y, dacc[9]);
                dacc[10] = fmaf(t1, w2.z, dacc[10]); dacc[11] = fmaf(t1, w2.w, dacc[11]);
                dacc[12] = fmaf(t1, w3.x, dacc[12]); dacc[13] = fmaf(t1, w3.y, dacc[13]);
                dacc[14] = fmaf(t1, w3.z, dacc[14]); dacc[15] = fmaf(t1, w3.w, dacc[15]);
            }
        }
    }
    wsync();

    // block reduction: dacc flat = lane*16+j
    {
        float4* fp = (float4*)&sA[lane * 16];
        fp[0] = make_float4(dacc[0],  dacc[1],  dacc[2],  dacc[3]);
        fp[1] = make_float4(dacc[4],  dacc[5],  dacc[6],  dacc[7]);
        fp[2] = make_float4(dacc[8],  dacc[9],  dacc[10], dacc[11]);
        fp[3] = make_float4(dacc[12], dacc[13], dacc[14], dacc[15]);
    }
    __syncthreads();
    if (threadIdx.x < 256) {
        int t = threadIdx.x;
        float4 s0 = ((float4*)sAall[0])[t];
        float4 s1 = ((float4*)sAall[1])[t];
        float4 s2 = ((float4*)sAall[2])[t];
        float4 s3 = ((float4*)sAall[3])[t];
        float4 s4 = ((float4*)sAall[4])[t];
        float4 s5 = ((float4*)sAall[5])[t];
        float4 s6 = ((float4*)sAall[6])[t];
        float4 s7 = ((float4*)sAall[7])[t];
        float4 s;
        s.x = ((s0.x + s1.x) + (s2.x + s3.x)) + ((s4.x + s5.x) + (s6.x + s7.x));
        s.y = ((s0.y + s1.y) + (s2.y + s3.y)) + ((s4.y + s5.y) + (s6.y + s7.y));
        s.z = ((s0.z + s1.z) + (s2.z + s3.z)) + ((s4.z + s5.z) + (s6.z + s7.z));
        s.w = ((s0.w + s1.w) + (s2.w + s3.w)) + ((s4.w + s5.w) + (s6.w + s7.w));
        ((float4*)(Part + (size_t)blockIdx.x * 1024))[t] = s;
    }
}

// ---------------- k31: fused G-update + eigh for next iteration ----------------

__global__ __launch_bounds__(64) void k31_update(float* __restrict__ G,
                                                 float* __restrict__ Gs,
                                                 float* __restrict__ Gis,
                                                 const float* __restrict__ Part,
                                                 float* __restrict__ norm_acc,
                                                 int* __restrict__ counter,
                                                 int* __restrict__ done) {
    if (*done) return;
    int b = blockIdx.x, lane = threadIdx.x;
    int c = lane & 31, h = lane >> 5;
    int aself = lane << 2, a32 = aself ^ 128;
    int r = lane >> 1, cb = (lane & 1) << 4;
    __shared__ __align__(16) float s0[DD * LD2], s1[DD * LD2], s2[DD * LD2];
    __shared__ float scg[DD], scs[DD], sci[DD];

    // Delta = sum of 16 partials / NN
    float d[16];
#pragma unroll
    for (int j = 0; j < 16; ++j) d[j] = 0.f;
#pragma unroll 1
    for (int g = 0; g < 16; ++g) {
        const float4* P = (const float4*)(Part + (size_t)(b * 16 + g) * 1024 + lane * 16);
        float4 p0 = P[0], p1 = P[1], p2 = P[2], p3 = P[3];
        d[0]+=p0.x; d[1]+=p0.y; d[2]+=p0.z; d[3]+=p0.w;
        d[4]+=p1.x; d[5]+=p1.y; d[6]+=p1.z; d[7]+=p1.w;
        d[8]+=p2.x; d[9]+=p2.y; d[10]+=p2.z; d[11]+=p2.w;
        d[12]+=p3.x; d[13]+=p3.y; d[14]+=p3.z; d[15]+=p3.w;
    }
    const float inv = 1.0f / NN;
    float sumsq = 0.f;
#pragma unroll
    for (int j = 0; j < 16; ++j) { d[j] *= inv; sumsq = fmaf(d[j], d[j], sumsq); }
#pragma unroll
    for (int sh = 1; sh <= 32; sh <<= 1) sumsq += bpf(aself ^ (sh << 2), sumsq);
    if (lane == 0) atomicAdd(norm_acc, sqrtf(sumsq));

    // Delta -> s0
    {
        float4* dp = (float4*)&s0[r * LD2 + cb];
        dp[0] = make_float4(d[0],  d[1],  d[2],  d[3]);
        dp[1] = make_float4(d[4],  d[5],  d[6],  d[7]);
        dp[2] = make_float4(d[8],  d[9],  d[10], d[11]);
        dp[3] = make_float4(d[12], d[13], d[14], d[15]);
    }
    wsync();

    // expm_taylor order 5
    float outr[16];
#pragma unroll
    for (int j = 0; j < 16; ++j)
        outr[j] = ((cb + j) == r ? 1.0f : 0.0f) + d[j];
    float fac = 1.0f;
#pragma unroll 1
    for (int i = 2; i <= 5; ++i) {
        fac *= (float)i;
        float acc[16];
#pragma unroll
        for (int j = 0; j < 16; ++j) acc[j] = 0.f;
        const float* Xp = (i == 2) ? s0 : s1;
        for (int k = 0; k < DD; ++k) {
            float av = Xp[r * LD2 + k];
            const float4* Br = (const float4*)&s0[k * LD2 + cb];
            float4 b0 = Br[0], b1 = Br[1], b2 = Br[2], b3 = Br[3];
            acc[0]+=av*b0.x; acc[1]+=av*b0.y; acc[2]+=av*b0.z; acc[3]+=av*b0.w;
            acc[4]+=av*b1.x; acc[5]+=av*b1.y; acc[6]+=av*b1.z; acc[7]+=av*b1.w;
            acc[8]+=av*b2.x; acc[9]+=av*b2.y; acc[10]+=av*b2.z; acc[11]+=av*b2.w;
            acc[12]+=av*b3.x; acc[13]+=av*b3.y; acc[14]+=av*b3.z; acc[15]+=av*b3.w;
        }
        float invf = 1.0f / fac;
#pragma unroll
        for (int j = 0; j < 16; ++j) outr[j] = fmaf(acc[j], invf, outr[j]);
        wsync();
        float4* dp = (float4*)&s1[r * LD2 + cb];
        dp[0] = make_float4(acc[0],  acc[1],  acc[2],  acc[3]);
        dp[1] = make_float4(acc[4],  acc[5],  acc[6],  acc[7]);
        dp[2] = make_float4(acc[8],  acc[9],  acc[10], acc[11]);
        dp[3] = make_float4(acc[12], acc[13], acc[14], acc[15]);
        wsync();
    }
    // E -> s0; Gs_old -> s1
    {
        float4* dp = (float4*)&s0[r * LD2 + cb];
        dp[0] = make_float4(outr[0],  outr[1],  outr[2],  outr[3]);
        dp[1] = make_float4(outr[4],  outr[5],  outr[6],  outr[7]);
        dp[2] = make_float4(outr[8],  outr[9],  outr[10], outr[11]);
        dp[3] = make_float4(outr[12], outr[13], outr[14], outr[15]);
        const float4* Gsb = (const float4*)(Gs + b * 1024);
#pragma unroll
        for (int j4 = 0; j4 < 4; ++j4) {
            float4 v = Gsb[lane * 4 + j4];
            int e = lane * 16 + j4 * 4;
            *((float4*)&s1[(e >> 5) * LD2 + (e & 31)]) = v;
        }
    }
    wsync();
    mm32w(s1, s0, s2, lane);   // T = Gs * E
    mm32w(s2, s1, s0, lane);   // M = T * Gs

    // enforce_spd eigh: extract col with symmetrize + jitter
    float a[16];
#pragma unroll
    for (int i = 0; i < 16; ++i) {
        int row = 16 * h + i;
        float own = s0[c * LD2 + row];
        float v = 0.5f * (s0[row * LD2 + c] + own);
        if (row == c) v = own + JIT;
        a[i] = v;
    }
    jac1(a, aself, a32, c, 10, 1e-12f);
    float gs2 = 0.f;
#pragma unroll
    for (int i = 0; i < 16; ++i) gs2 = fmaf(a[i], a[i], gs2);
    gs2 += bpf(a32, gs2);
    float l = __builtin_amdgcn_sqrtf(gs2);
    float clipl = fmaxf(l, JIT);
    float ig = __builtin_amdgcn_rcpf(gs2);
    float tg = clipl * ig;                      // G:   clip(lam)/lam^2
    float sh = clipl + JIT;                     // next eigh's vals (same eigvecs)
    float ts = __builtin_amdgcn_sqrtf(sh) * ig; // Gs:  sqrt(clip+JIT)/lam^2
    float ti = __builtin_amdgcn_rsqf(sh) * ig;  // Gis: rsqrt(clip+JIT)/lam^2
    wsync();
    {
        float4* wp = (float4*)&s1[c * LD2 + 16 * h];
        wp[0] = make_float4(a[0],  a[1],  a[2],  a[3]);
        wp[1] = make_float4(a[4],  a[5],  a[6],  a[7]);
        wp[2] = make_float4(a[8],  a[9],  a[10], a[11]);
        wp[3] = make_float4(a[12], a[13], a[14], a[15]);
        if (h == 0) { scg[c] = tg; scs[c] = ts; sci[c] = ti; }
    }
    wsync();
    float gg[16], gsv[16], giv[16];
#pragma unroll
    for (int j = 0; j < 16; ++j) { gg[j] = 0.f; gsv[j] = 0.f; giv[j] = 0.f; }
    for (int k = 0; k < DD; ++k) {
        float wr = s1[k * LD2 + r];
        float cg = wr * scg[k], cs2 = wr * scs[k], ci = wr * sci[k];
        const float4* Wc = (const float4*)&s1[k * LD2 + cb];
        float4 w0 = Wc[0], w1 = Wc[1], w2 = Wc[2], w3 = Wc[3];
        gg[0]+=cg*w0.x; gsv[0]+=cs2*w0.x; giv[0]+=ci*w0.x;
        gg[1]+=cg*w0.y; gsv[1]+=cs2*w0.y; giv[1]+=ci*w0.y;
        gg[2]+=cg*w0.z; gsv[2]+=cs2*w0.z; giv[2]+=ci*w0.z;
        gg[3]+=cg*w0.w; gsv[3]+=cs2*w0.w; giv[3]+=ci*w0.w;
        gg[4]+=cg*w1.x; gsv[4]+=cs2*w1.x; giv[4]+=ci*w1.x;
        gg[5]+=cg*w1.y; gsv[5]+=cs2*w1.y; giv[5]+=ci*w1.y;
        gg[6]+=cg*w1.z; gsv[6]+=cs2*w1.z; giv[6]+=ci*w1.z;
        gg[7]+=cg*w1.w; gsv[7]+=cs2*w1.w; giv[7]+=ci*w1.w;
        gg[8]+=cg*w2.x; gsv[8]+=cs2*w2.x; giv[8]+=ci*w2.x;
        gg[9]+=cg*w2.y; gsv[9]+=cs2*w2.y; giv[9]+=ci*w2.y;
        gg[10]+=cg*w2.z; gsv[10]+=cs2*w2.z; giv[10]+=ci*w2.z;
        gg[11]+=cg*w2.w; gsv[11]+=cs2*w2.w; giv[11]+=ci*w2.w;
        gg[12]+=cg*w3.x; gsv[12]+=cs2*w3.x; giv[12]+=ci*w3.x;
        gg[13]+=cg*w3.y; gsv[13]+=cs2*w3.y; giv[13]+=ci*w3.y;
        gg[14]+=cg*w3.z; gsv[14]+=cs2*w3.z; giv[14]+=ci*w3.z;
        gg[15]+=cg*w3.w; gsv[15]+=cs2*w3.w; giv[15]+=ci*w3.w;
    }
    float4* Gb   = (float4*)(G   + b * 1024 + lane * 16);
    float4* Gsb  = (float4*)(Gs  + b * 1024 + lane * 16);
    float4* Gib  = (float4*)(Gis + b * 1024 + lane * 16);
#pragma unroll
    for (int j4 = 0; j4 < 4; ++j4) {
        Gb[j4]  = make_float4(gg[4*j4],  gg[4*j4+1],  gg[4*j4+2],  gg[4*j4+3]);
        Gsb[j4] = make_float4(gsv[4*j4], gsv[4*j4+1], gsv[4*j4+2], gsv[4*j4+3]);
        Gib[j4] = make_float4(giv[4*j4], giv[4*j4+1], giv[4*j4+2], giv[4*j4+3]);
    }

    // convergence check by last-finishing block
    __threadfence();
    if (lane == 0) {
        int ret = atomicAdd(counter, 1);
        if (ret == BB - 1) {
            float nm = atomicAdd(norm_acc, 0.f);
            if (nm * (1.0f / BB) < TOLF) *done = 1;
            *norm_acc = 0.f;
            *counter = 0;
            __threadfence();
        }
    }
}

__global__ __launch_bounds__(256) void k5_out(const float* __restrict__ G, float* __restrict__ out) {
    int i = blockIdx.x * 256 + threadIdx.x;
    out[i] = G[i];
}

extern "C" void kernel_launch(void* const* d_in, const int* in_sizes, int n_in,
                              void* d_out, int out_size, void* d_ws, size_t ws_size,
                              hipStream_t stream) {
    const float* X = (const float*)d_in[0];
    float* ws = (float*)d_ws;
    float* G     = ws;                        // 65536
    float* Gs    = ws + 65536;                // 65536
    float* Gis   = ws + 2 * 65536;            // 65536
    float* Part  = ws + 3 * 65536;            // 1024 blocks * 1024 = 1048576
    float* norm_acc = ws + 3 * 65536 + 1048576;
    int*   counter  = (int*)(norm_acc + 1);
    int*   done     = (int*)(norm_acc + 2);
    // V warm-start buffer: 64*512*1024 floats = 128 MB, only if d_ws is big enough
    size_t base_floats = (size_t)3 * 65536 + 1048576 + 16;
    size_t need_bytes = (base_floats + (size_t)BB * NN * 1024) * sizeof(float);
    float* Vbuf = (ws_size >= need_bytes) ? (ws + base_floats) : nullptr;

    k0_zero<<<64, 256, 0, stream>>>(G, done, norm_acc, counter);
    k0_mean<<<512, 256, 0, stream>>>(X, G);
    k1_init<<<64, 64, 0, stream>>>(G, Gs, Gis);
    for (int it = 0; it < MAXIT; ++it) {
        int it_eff = (Vbuf != nullptr) ? it : 0;
        k2_log_acc<<<1024, 512, 0, stream>>>(X, Gis, Part, done, Vbuf, it_eff);
        k31_update<<<64, 64, 0, stream>>>(G, Gs, Gis, Part, norm_acc, counter, done);
    }
    k5_out<<<256, 256, 0, stream>>>(G, (float*)d_out);
}

// Round 10
// 4902.202 us; speedup vs baseline: 1.6209x; 1.0851x over previous
//
#include <hip/hip_runtime.h>
#include <math.h>

#define BB 64
#define NN 512
#define DD 32
#define LD2 36           // sA leading dim (pad col 32 holds per-column tk)
#define LDG 32           // sG leading dim (broadcast/bank-r reads only)
#define JIT 1e-5f
#define TOLF 1e-4f
#define MAXIT 10

// lane-pull via LDS permute unit; addr = src_lane<<2
__device__ __forceinline__ float bpf(int addr, float v) {
    return __int_as_float(__builtin_amdgcn_ds_bpermute(addr, __float_as_int(v)));
}

__device__ __forceinline__ void wsync() {
    // wave-level LDS handoff (single-wave or per-wave-buffer use only)
    __asm__ volatile("s_waitcnt lgkmcnt(0)" ::: "memory");
}

// ---------------- one-sided (Hestenes) Jacobi, register-resident ----------------
__device__ __forceinline__ void jac1(float a[16], int aself, int a32, int c,
                                     int maxsweep, float thr) {
#pragma unroll 1
    for (int sweep = 0; sweep < maxsweep; ++sweep) {
        float maxrel = 0.f;
#pragma unroll 1
        for (int m = 1; m < 32; ++m) {
            int am = aself ^ (m << 2);
            float pa[16];
#pragma unroll
            for (int i = 0; i < 16; ++i) pa[i] = bpf(am, a[i]);
            float gs = 0.f, gc = 0.f;
#pragma unroll
            for (int i = 0; i < 16; ++i) {
                gs = fmaf(a[i], a[i], gs);
                gc = fmaf(a[i], pa[i], gc);
            }
            gs += bpf(a32, gs);
            gc += bpf(a32, gc);
            float gp = bpf(am, gs);
            bool isP = c < (c ^ m);
            float gpp = isP ? gs : gp;
            float gqq = isP ? gp : gs;
            float rel = gc * gc * __builtin_amdgcn_rcpf(gpp * gqq);
            maxrel = fmaxf(maxrel, rel);
            float tau = (gqq - gpp) * (0.5f * __builtin_amdgcn_rcpf(gc));
            float den = fabsf(tau) + __builtin_amdgcn_sqrtf(fmaf(tau, tau, 1.f));
            float tt  = copysignf(__builtin_amdgcn_rcpf(den), tau);
            tt = (rel > 1e-24f) ? tt : 0.f;
            float cs  = __builtin_amdgcn_rsqf(fmaf(tt, tt, 1.f));
            float sn  = tt * cs;
            float sg = isP ? -sn : sn;
#pragma unroll
            for (int i = 0; i < 16; ++i) a[i] = fmaf(sg, pa[i], cs * a[i]);
        }
#pragma unroll
        for (int sh = 1; sh <= 32; sh <<= 1)
            maxrel = fmaxf(maxrel, bpf(aself ^ (sh << 2), maxrel));
        if (maxrel < thr) break;
    }
}

// C = A * B (32x32, both stride LD2). Wave-synchronous, in-place safe (single wave).
__device__ __forceinline__ void mm32w(const float* A, const float* B, float* C, int lane) {
    int r = lane >> 1, cb = (lane & 1) << 4;
    float acc[16];
#pragma unroll
    for (int j = 0; j < 16; ++j) acc[j] = 0.0f;
    for (int k = 0; k < DD; ++k) {
        float a = A[r * LD2 + k];
        const float4* Br = (const float4*)(B + k * LD2 + cb);
        float4 b0 = Br[0], b1 = Br[1], b2 = Br[2], b3 = Br[3];
        acc[0]  = fmaf(a, b0.x, acc[0]);  acc[1]  = fmaf(a, b0.y, acc[1]);
        acc[2]  = fmaf(a, b0.z, acc[2]);  acc[3]  = fmaf(a, b0.w, acc[3]);
        acc[4]  = fmaf(a, b1.x, acc[4]);  acc[5]  = fmaf(a, b1.y, acc[5]);
        acc[6]  = fmaf(a, b1.z, acc[6]);  acc[7]  = fmaf(a, b1.w, acc[7]);
        acc[8]  = fmaf(a, b2.x, acc[8]);  acc[9]  = fmaf(a, b2.y, acc[9]);
        acc[10] = fmaf(a, b2.z, acc[10]); acc[11] = fmaf(a, b2.w, acc[11]);
        acc[12] = fmaf(a, b3.x, acc[12]); acc[13] = fmaf(a, b3.y, acc[13]);
        acc[14] = fmaf(a, b3.z, acc[14]); acc[15] = fmaf(a, b3.w, acc[15]);
    }
    wsync();
    float4* Cr = (float4*)(C + r * LD2 + cb);
    Cr[0] = make_float4(acc[0],  acc[1],  acc[2],  acc[3]);
    Cr[1] = make_float4(acc[4],  acc[5],  acc[6],  acc[7]);
    Cr[2] = make_float4(acc[8],  acc[9],  acc[10], acc[11]);
    Cr[3] = make_float4(acc[12], acc[13], acc[14], acc[15]);
    wsync();
}

// ---------------- setup ----------------

__global__ __launch_bounds__(256) void k0_zero(float* __restrict__ G, int* __restrict__ done,
                                               float* __restrict__ norm_acc, int* __restrict__ counter) {
    float4* Gb = (float4*)(G + blockIdx.x * 1024);
    Gb[threadIdx.x] = make_float4(0.f, 0.f, 0.f, 0.f);
    if (blockIdx.x == 0 && threadIdx.x == 0) { *done = 0; *norm_acc = 0.f; *counter = 0; }
}

__global__ __launch_bounds__(256) void k0_mean(const float* __restrict__ X, float* __restrict__ G) {
    int blk = blockIdx.x;
    int b = blk >> 3, chunk = blk & 7;
    int t = threadIdx.x;
    const float4* Xb = (const float4*)(X + ((size_t)(b * NN + chunk * 64)) * 1024);
    float4 acc = make_float4(0.f, 0.f, 0.f, 0.f);
    for (int n = 0; n < 64; ++n) {
        float4 v = Xb[n * 256 + t];
        acc.x += v.x; acc.y += v.y; acc.z += v.z; acc.w += v.w;
    }
    const float inv = 1.0f / NN;
    float* Gb = G + b * 1024 + t * 4;
    atomicAdd(Gb + 0, acc.x * inv);
    atomicAdd(Gb + 1, acc.y * inv);
    atomicAdd(Gb + 2, acc.z * inv);
    atomicAdd(Gb + 3, acc.w * inv);
}

// ---------------- k1: initial eigh(G0) -> Gs, Gis; seed Vg (once) ----------------

__global__ __launch_bounds__(64) void k1_init(const float* __restrict__ G,
                                              float* __restrict__ Gs, float* __restrict__ Gis,
                                              float* __restrict__ Vg) {
    int b = blockIdx.x, lane = threadIdx.x;
    int c = lane & 31, h = lane >> 5;
    int aself = lane << 2, a32 = aself ^ 128;
    int r = lane >> 1, cb = (lane & 1) << 4;
    __shared__ __align__(16) float sW[DD * LD2];
    __shared__ float sc1[DD], sc2[DD];

    float a[16];
    {
        const float4* Gc = (const float4*)(G + b * 1024 + c * 32 + 16 * h);
        float4 v0 = Gc[0], v1 = Gc[1], v2 = Gc[2], v3 = Gc[3];
        a[0]=v0.x; a[1]=v0.y; a[2]=v0.z; a[3]=v0.w;
        a[4]=v1.x; a[5]=v1.y; a[6]=v1.z; a[7]=v1.w;
        a[8]=v2.x; a[9]=v2.y; a[10]=v2.z; a[11]=v2.w;
        a[12]=v3.x; a[13]=v3.y; a[14]=v3.z; a[15]=v3.w;
#pragma unroll
        for (int i = 0; i < 16; ++i)
            if (16 * h + i == c) a[i] += JIT;   // _safe_eigh jitter
    }
    jac1(a, aself, a32, c, 10, 1e-12f);
    float gs2 = 0.f;
#pragma unroll
    for (int i = 0; i < 16; ++i) gs2 = fmaf(a[i], a[i], gs2);
    gs2 += bpf(a32, gs2);
    float l  = __builtin_amdgcn_sqrtf(gs2);
    float lc = fmaxf(l, JIT);
    float ig = __builtin_amdgcn_rcpf(gs2);
    float c1 = __builtin_amdgcn_sqrtf(lc) * ig;   // sqrt(clip(lam)) / lam^2
    float c2 = __builtin_amdgcn_rsqf(lc) * ig;    // 1/sqrt(clip(lam)) / lam^2
    if (Vg) {   // seed warm-start basis for k31
        float inl = __builtin_amdgcn_rsqf(gs2);
        float4* Vp = (float4*)(Vg + b * 1024 + c * 32 + 16 * h);
        Vp[0] = make_float4(a[0]*inl,  a[1]*inl,  a[2]*inl,  a[3]*inl);
        Vp[1] = make_float4(a[4]*inl,  a[5]*inl,  a[6]*inl,  a[7]*inl);
        Vp[2] = make_float4(a[8]*inl,  a[9]*inl,  a[10]*inl, a[11]*inl);
        Vp[3] = make_float4(a[12]*inl, a[13]*inl, a[14]*inl, a[15]*inl);
    }
    {
        float4* wp = (float4*)&sW[c * LD2 + 16 * h];
        wp[0] = make_float4(a[0],  a[1],  a[2],  a[3]);
        wp[1] = make_float4(a[4],  a[5],  a[6],  a[7]);
        wp[2] = make_float4(a[8],  a[9],  a[10], a[11]);
        wp[3] = make_float4(a[12], a[13], a[14], a[15]);
        if (h == 0) { sc1[c] = c1; sc2[c] = c2; }
    }
    wsync();
    float a1[16], a2[16];
#pragma unroll
    for (int j = 0; j < 16; ++j) { a1[j] = 0.f; a2[j] = 0.f; }
    for (int k = 0; k < DD; ++k) {
        float wr = sW[k * LD2 + r];
        float t1 = wr * sc1[k], t2 = wr * sc2[k];
        const float4* Wc = (const float4*)&sW[k * LD2 + cb];
        float4 w0 = Wc[0], w1 = Wc[1], w2 = Wc[2], w3 = Wc[3];
        a1[0]+=t1*w0.x; a2[0]+=t2*w0.x;  a1[1]+=t1*w0.y; a2[1]+=t2*w0.y;
        a1[2]+=t1*w0.z; a2[2]+=t2*w0.z;  a1[3]+=t1*w0.w; a2[3]+=t2*w0.w;
        a1[4]+=t1*w1.x; a2[4]+=t2*w1.x;  a1[5]+=t1*w1.y; a2[5]+=t2*w1.y;
        a1[6]+=t1*w1.z; a2[6]+=t2*w1.z;  a1[7]+=t1*w1.w; a2[7]+=t2*w1.w;
        a1[8]+=t1*w2.x; a2[8]+=t2*w2.x;  a1[9]+=t1*w2.y; a2[9]+=t2*w2.y;
        a1[10]+=t1*w2.z; a2[10]+=t2*w2.z; a1[11]+=t1*w2.w; a2[11]+=t2*w2.w;
        a1[12]+=t1*w3.x; a2[12]+=t2*w3.x; a1[13]+=t1*w3.y; a2[13]+=t2*w3.y;
        a1[14]+=t1*w3.z; a2[14]+=t2*w3.z; a1[15]+=t1*w3.w; a2[15]+=t2*w3.w;
    }
    float4* Gsb  = (float4*)(Gs  + b * 1024 + lane * 16);
    float4* Gisb = (float4*)(Gis + b * 1024 + lane * 16);
#pragma unroll
    for (int j4 = 0; j4 < 4; ++j4) {
        Gsb[j4]  = make_float4(a1[4*j4], a1[4*j4+1], a1[4*j4+2], a1[4*j4+3]);
        Gisb[j4] = make_float4(a2[4*j4], a2[4*j4+1], a2[4*j4+2], a2[4*j4+3]);
    }
}

// ---------------- k2: hot kernel ----------------
// 1024 blocks x 8 waves; wave handles 4 matrices. it>0: warm-start Jacobi with V
// from the previous outer iteration (Vbuf, 128 MB in d_ws). it==0 (or no Vbuf
// capacity): cold start from columns of A.

__global__ __launch_bounds__(512) void k2_log_acc(const float* __restrict__ X,
                                                  const float* __restrict__ Gis,
                                                  float* __restrict__ Part,
                                                  const int* __restrict__ done,
                                                  float* __restrict__ Vbuf,
                                                  int it) {
    if (*done) return;
    int b = blockIdx.x >> 4, grp = blockIdx.x & 15;
    int wv = threadIdx.x >> 6, lane = threadIdx.x & 63;
    int c = lane & 31, h = lane >> 5;
    int aself = lane << 2, a32 = aself ^ 128;

    __shared__ __align__(16) float sG[DD * LDG];           // 4096 B
    __shared__ __align__(16) float sAall[8][DD * LD2];     // 36864 B
    float* sA = sAall[wv];

    if (threadIdx.x < 256)
        ((float4*)sG)[threadIdx.x] = ((const float4*)(Gis + b * 1024))[threadIdx.x];
    __syncthreads();

    int r = lane >> 1, cb = (lane & 1) << 4;
    float dacc[16];
#pragma unroll
    for (int j = 0; j < 16; ++j) dacc[j] = 0.f;

#pragma unroll 1
    for (int nn = 0; nn < 4; ++nn) {
        int n = grp * 32 + wv * 4 + nn;
        // ---- stage X[b,n] -> sA ----
        {
            const float4* Xv = (const float4*)(X + ((size_t)(b * NN + n)) * 1024);
            float4 v0 = Xv[lane * 4 + 0], v1 = Xv[lane * 4 + 1];
            float4 v2 = Xv[lane * 4 + 2], v3 = Xv[lane * 4 + 3];
            wsync();   // all prior readers of sA done
            int e = lane * 16;
            float* d0 = &sA[(e >> 5) * LD2 + (e & 31)];
            *((float4*)d0)        = v0;
            *((float4*)(d0 + 4))  = v1;
            *((float4*)(d0 + 8))  = v2;
            *((float4*)(d0 + 12)) = v3;
            wsync();
        }
        // ---- T = Gis * X (A-operand transposed read from sG: conflict-free) ----
        {
            float acc[16];
#pragma unroll
            for (int j = 0; j < 16; ++j) acc[j] = 0.f;
            for (int k = 0; k < DD; ++k) {
                float a = sG[k * LDG + r];
                const float4* Br = (const float4*)(sA + k * LD2 + cb);
                float4 b0 = Br[0], b1 = Br[1], b2 = Br[2], b3 = Br[3];
                acc[0]  = fmaf(a, b0.x, acc[0]);  acc[1]  = fmaf(a, b0.y, acc[1]);
                acc[2]  = fmaf(a, b0.z, acc[2]);  acc[3]  = fmaf(a, b0.w, acc[3]);
                acc[4]  = fmaf(a, b1.x, acc[4]);  acc[5]  = fmaf(a, b1.y, acc[5]);
                acc[6]  = fmaf(a, b1.z, acc[6]);  acc[7]  = fmaf(a, b1.w, acc[7]);
                acc[8]  = fmaf(a, b2.x, acc[8]);  acc[9]  = fmaf(a, b2.y, acc[9]);
                acc[10] = fmaf(a, b2.z, acc[10]); acc[11] = fmaf(a, b2.w, acc[11]);
                acc[12] = fmaf(a, b3.x, acc[12]); acc[13] = fmaf(a, b3.y, acc[13]);
                acc[14] = fmaf(a, b3.z, acc[14]); acc[15] = fmaf(a, b3.w, acc[15]);
            }
            wsync();
            float4* Cr = (float4*)(sA + r * LD2 + cb);
            Cr[0] = make_float4(acc[0],  acc[1],  acc[2],  acc[3]);
            Cr[1] = make_float4(acc[4],  acc[5],  acc[6],  acc[7]);
            Cr[2] = make_float4(acc[8],  acc[9],  acc[10], acc[11]);
            Cr[3] = make_float4(acc[12], acc[13], acc[14], acc[15]);
            wsync();
        }
        // ---- A = T * Gis ----
        {
            float acc[16];
#pragma unroll
            for (int j = 0; j < 16; ++j) acc[j] = 0.f;
            for (int k = 0; k < DD; ++k) {
                float a = sA[r * LD2 + k];
                const float4* Br = (const float4*)(sG + k * LDG + cb);
                float4 b0 = Br[0], b1 = Br[1], b2 = Br[2], b3 = Br[3];
                acc[0]  = fmaf(a, b0.x, acc[0]);  acc[1]  = fmaf(a, b0.y, acc[1]);
                acc[2]  = fmaf(a, b0.z, acc[2]);  acc[3]  = fmaf(a, b0.w, acc[3]);
                acc[4]  = fmaf(a, b1.x, acc[4]);  acc[5]  = fmaf(a, b1.y, acc[5]);
                acc[6]  = fmaf(a, b1.z, acc[6]);  acc[7]  = fmaf(a, b1.w, acc[7]);
                acc[8]  = fmaf(a, b2.x, acc[8]);  acc[9]  = fmaf(a, b2.y, acc[9]);
                acc[10] = fmaf(a, b2.z, acc[10]); acc[11] = fmaf(a, b2.w, acc[11]);
                acc[12] = fmaf(a, b3.x, acc[12]); acc[13] = fmaf(a, b3.y, acc[13]);
                acc[14] = fmaf(a, b3.z, acc[14]); acc[15] = fmaf(a, b3.w, acc[15]);
            }
            wsync();
            float4* Cr = (float4*)(sA + r * LD2 + cb);
            Cr[0] = make_float4(acc[0],  acc[1],  acc[2],  acc[3]);
            Cr[1] = make_float4(acc[4],  acc[5],  acc[6],  acc[7]);
            Cr[2] = make_float4(acc[8],  acc[9],  acc[10], acc[11]);
            Cr[3] = make_float4(acc[12], acc[13], acc[14], acc[15]);
            wsync();
        }
        // ---- initial W columns: cold (A cols, symmetrized) or warm (A * V_prev) ----
        float a[16];
        if (it == 0) {
            const float4* cp = (const float4*)&sA[c * LD2 + 16 * h];
            float4 t0 = cp[0], t1 = cp[1], t2 = cp[2], t3 = cp[3];
            float tr[16] = { t0.x,t0.y,t0.z,t0.w, t1.x,t1.y,t1.z,t1.w,
                             t2.x,t2.y,t2.z,t2.w, t3.x,t3.y,t3.z,t3.w };
#pragma unroll
            for (int i = 0; i < 16; ++i) {
                int row = 16 * h + i;
                float v = 0.5f * (sA[row * LD2 + c] + tr[i]);
                if (row == c) v = tr[i] + JIT;
                a[i] = v;
            }
        } else {
            // w_c = (A + JIT I) * vhat_prev_c ; vhat in registers, A rows broadcast from LDS
            float v[32];
            {
                const float4* Vp = (const float4*)(Vbuf + ((size_t)(b * NN + n)) * 1024 + c * 32);
#pragma unroll
                for (int j4 = 0; j4 < 8; ++j4) {
                    float4 t = Vp[j4];
                    v[4*j4] = t.x; v[4*j4+1] = t.y; v[4*j4+2] = t.z; v[4*j4+3] = t.w;
                }
            }
#pragma unroll
            for (int i = 0; i < 16; ++i) {
                const float4* Ar = (const float4*)&sA[(16 * h + i) * LD2];
                float s = 0.f;
#pragma unroll
                for (int j4 = 0; j4 < 8; ++j4) {
                    float4 q = Ar[j4];
                    s = fmaf(q.x, v[4*j4],   s);
                    s = fmaf(q.y, v[4*j4+1], s);
                    s = fmaf(q.z, v[4*j4+2], s);
                    s = fmaf(q.w, v[4*j4+3], s);
                }
                a[i] = fmaf(JIT, v[16 * h + i], s);
            }
        }

        jac1(a, aself, a32, c, 8, (it == 0) ? 3e-10f : 1e-8f);

        // ---- eigen extraction + V store + rebuild ----
        {
            float gs2 = 0.f;
#pragma unroll
            for (int i = 0; i < 16; ++i) gs2 = fmaf(a[i], a[i], gs2);
            gs2 += bpf(a32, gs2);
            float gs2c = fmaxf(gs2, JIT * JIT);
            float tk = 0.5f * logf(gs2c) * __builtin_amdgcn_rcpf(gs2);
            if (Vbuf) {   // store normalized eigenvectors for next iteration's warm start
                float inl = __builtin_amdgcn_rsqf(gs2);
                float4* Vp = (float4*)(Vbuf + ((size_t)(b * NN + n)) * 1024 + c * 32 + 16 * h);
                Vp[0] = make_float4(a[0]*inl,  a[1]*inl,  a[2]*inl,  a[3]*inl);
                Vp[1] = make_float4(a[4]*inl,  a[5]*inl,  a[6]*inl,  a[7]*inl);
                Vp[2] = make_float4(a[8]*inl,  a[9]*inl,  a[10]*inl, a[11]*inl);
                Vp[3] = make_float4(a[12]*inl, a[13]*inl, a[14]*inl, a[15]*inl);
            }
            wsync();   // prior readers of sA done
            float4* wp = (float4*)&sA[c * LD2 + 16 * h];
            wp[0] = make_float4(a[0],  a[1],  a[2],  a[3]);
            wp[1] = make_float4(a[4],  a[5],  a[6],  a[7]);
            wp[2] = make_float4(a[8],  a[9],  a[10], a[11]);
            wp[3] = make_float4(a[12], a[13], a[14], a[15]);
            if (h == 0) sA[c * LD2 + 32] = tk;          // tk in row padding
            wsync();
            for (int k = 0; k < DD; ++k) {
                float t1 = sA[k * LD2 + r] * sA[k * LD2 + 32];
                const float4* Wr = (const float4*)&sA[k * LD2 + cb];
                float4 w0 = Wr[0], w1 = Wr[1], w2 = Wr[2], w3 = Wr[3];
                dacc[0]  = fmaf(t1, w0.x, dacc[0]);  dacc[1]  = fmaf(t1, w0.y, dacc[1]);
                dacc[2]  = fmaf(t1, w0.z, dacc[2]);  dacc[3]  = fmaf(t1, w0.w, dacc[3]);
                dacc[4]  = fmaf(t1, w1.x, dacc[4]);  dacc[5]  = fmaf(t1, w1.y, dacc[5]);
                dacc[6]  = fmaf(t1, w1.z, dacc[6]);  dacc[7]  = fmaf(t1, w1.w, dacc[7]);
                dacc[8]  = fmaf(t1, w2.x, dacc[8]);  dacc[9]  = fmaf(t1, w2.y, dacc[9]);
                dacc[10] = fmaf(t1, w2.z, dacc[10]); dacc[11] = fmaf(t1, w2.w, dacc[11]);
                dacc[12] = fmaf(t1, w3.x, dacc[12]); dacc[13] = fmaf(t1, w3.y, dacc[13]);
                dacc[14] = fmaf(t1, w3.z, dacc[14]); dacc[15] = fmaf(t1, w3.w, dacc[15]);
            }
        }
    }
    wsync();

    // block reduction: dacc flat = lane*16+j
    {
        float4* fp = (float4*)&sA[lane * 16];
        fp[0] = make_float4(dacc[0],  dacc[1],  dacc[2],  dacc[3]);
        fp[1] = make_float4(dacc[4],  dacc[5],  dacc[6],  dacc[7]);
        fp[2] = make_float4(dacc[8],  dacc[9],  dacc[10], dacc[11]);
        fp[3] = make_float4(dacc[12], dacc[13], dacc[14], dacc[15]);
    }
    __syncthreads();
    if (threadIdx.x < 256) {
        int t = threadIdx.x;
        float4 s0 = ((float4*)sAall[0])[t];
        float4 s1 = ((float4*)sAall[1])[t];
        float4 s2 = ((float4*)sAall[2])[t];
        float4 s3 = ((float4*)sAall[3])[t];
        float4 s4 = ((float4*)sAall[4])[t];
        float4 s5 = ((float4*)sAall[5])[t];
        float4 s6 = ((float4*)sAall[6])[t];
        float4 s7 = ((float4*)sAall[7])[t];
        float4 s;
        s.x = ((s0.x + s1.x) + (s2.x + s3.x)) + ((s4.x + s5.x) + (s6.x + s7.x));
        s.y = ((s0.y + s1.y) + (s2.y + s3.y)) + ((s4.y + s5.y) + (s6.y + s7.y));
        s.z = ((s0.z + s1.z) + (s2.z + s3.z)) + ((s4.z + s5.z) + (s6.z + s7.z));
        s.w = ((s0.w + s1.w) + (s2.w + s3.w)) + ((s4.w + s5.w) + (s6.w + s7.w));
        ((float4*)(Part + (size_t)blockIdx.x * 1024))[t] = s;
    }
}

// ---------------- k31: fused G-update + eigh for next iteration ----------------
// Warm-starts its eigh with the previous M's eigenvectors (Vg; seeded by k1_init).

__global__ __launch_bounds__(64) void k31_update(float* __restrict__ G,
                                                 float* __restrict__ Gs,
                                                 float* __restrict__ Gis,
                                                 const float* __restrict__ Part,
                                                 float* __restrict__ norm_acc,
                                                 int* __restrict__ counter,
                                                 int* __restrict__ done,
                                                 float* __restrict__ Vg) {
    if (*done) return;
    int b = blockIdx.x, lane = threadIdx.x;
    int c = lane & 31, h = lane >> 5;
    int aself = lane << 2, a32 = aself ^ 128;
    int r = lane >> 1, cb = (lane & 1) << 4;
    __shared__ __align__(16) float s0[DD * LD2], s1[DD * LD2], s2[DD * LD2];
    __shared__ float scg[DD], scs[DD], sci[DD];

    // Delta = sum of 16 partials / NN
    float d[16];
#pragma unroll
    for (int j = 0; j < 16; ++j) d[j] = 0.f;
#pragma unroll 1
    for (int g = 0; g < 16; ++g) {
        const float4* P = (const float4*)(Part + (size_t)(b * 16 + g) * 1024 + lane * 16);
        float4 p0 = P[0], p1 = P[1], p2 = P[2], p3 = P[3];
        d[0]+=p0.x; d[1]+=p0.y; d[2]+=p0.z; d[3]+=p0.w;
        d[4]+=p1.x; d[5]+=p1.y; d[6]+=p1.z; d[7]+=p1.w;
        d[8]+=p2.x; d[9]+=p2.y; d[10]+=p2.z; d[11]+=p2.w;
        d[12]+=p3.x; d[13]+=p3.y; d[14]+=p3.z; d[15]+=p3.w;
    }
    const float inv = 1.0f / NN;
    float sumsq = 0.f;
#pragma unroll
    for (int j = 0; j < 16; ++j) { d[j] *= inv; sumsq = fmaf(d[j], d[j], sumsq); }
#pragma unroll
    for (int sh = 1; sh <= 32; sh <<= 1) sumsq += bpf(aself ^ (sh << 2), sumsq);
    if (lane == 0) atomicAdd(norm_acc, sqrtf(sumsq));

    // Delta -> s0
    {
        float4* dp = (float4*)&s0[r * LD2 + cb];
        dp[0] = make_float4(d[0],  d[1],  d[2],  d[3]);
        dp[1] = make_float4(d[4],  d[5],  d[6],  d[7]);
        dp[2] = make_float4(d[8],  d[9],  d[10], d[11]);
        dp[3] = make_float4(d[12], d[13], d[14], d[15]);
    }
    wsync();

    // expm_taylor order 5
    float outr[16];
#pragma unroll
    for (int j = 0; j < 16; ++j)
        outr[j] = ((cb + j) == r ? 1.0f : 0.0f) + d[j];
    float fac = 1.0f;
#pragma unroll 1
    for (int i = 2; i <= 5; ++i) {
        fac *= (float)i;
        float acc[16];
#pragma unroll
        for (int j = 0; j < 16; ++j) acc[j] = 0.f;
        const float* Xp = (i == 2) ? s0 : s1;
        for (int k = 0; k < DD; ++k) {
            float av = Xp[r * LD2 + k];
            const float4* Br = (const float4*)&s0[k * LD2 + cb];
            float4 b0 = Br[0], b1 = Br[1], b2 = Br[2], b3 = Br[3];
            acc[0]+=av*b0.x; acc[1]+=av*b0.y; acc[2]+=av*b0.z; acc[3]+=av*b0.w;
            acc[4]+=av*b1.x; acc[5]+=av*b1.y; acc[6]+=av*b1.z; acc[7]+=av*b1.w;
            acc[8]+=av*b2.x; acc[9]+=av*b2.y; acc[10]+=av*b2.z; acc[11]+=av*b2.w;
            acc[12]+=av*b3.x; acc[13]+=av*b3.y; acc[14]+=av*b3.z; acc[15]+=av*b3.w;
        }
        float invf = 1.0f / fac;
#pragma unroll
        for (int j = 0; j < 16; ++j) outr[j] = fmaf(acc[j], invf, outr[j]);
        wsync();
        float4* dp = (float4*)&s1[r * LD2 + cb];
        dp[0] = make_float4(acc[0],  acc[1],  acc[2],  acc[3]);
        dp[1] = make_float4(acc[4],  acc[5],  acc[6],  acc[7]);
        dp[2] = make_float4(acc[8],  acc[9],  acc[10], acc[11]);
        dp[3] = make_float4(acc[12], acc[13], acc[14], acc[15]);
        wsync();
    }
    // E -> s0; Gs_old -> s1
    {
        float4* dp = (float4*)&s0[r * LD2 + cb];
        dp[0] = make_float4(outr[0],  outr[1],  outr[2],  outr[3]);
        dp[1] = make_float4(outr[4],  outr[5],  outr[6],  outr[7]);
        dp[2] = make_float4(outr[8],  outr[9],  outr[10], outr[11]);
        dp[3] = make_float4(outr[12], outr[13], outr[14], outr[15]);
        const float4* Gsb = (const float4*)(Gs + b * 1024);
#pragma unroll
        for (int j4 = 0; j4 < 4; ++j4) {
            float4 v = Gsb[lane * 4 + j4];
            int e = lane * 16 + j4 * 4;
            *((float4*)&s1[(e >> 5) * LD2 + (e & 31)]) = v;
        }
    }
    wsync();
    mm32w(s1, s0, s2, lane);   // T = Gs * E
    mm32w(s2, s1, s0, lane);   // M = T * Gs

    // enforce_spd eigh: cold (symmetrized cols) or warm (M * Vg + JIT Vg)
    float a[16];
    if (Vg == nullptr) {
#pragma unroll
        for (int i = 0; i < 16; ++i) {
            int row = 16 * h + i;
            float own = s0[c * LD2 + row];
            float v = 0.5f * (s0[row * LD2 + c] + own);
            if (row == c) v = own + JIT;
            a[i] = v;
        }
    } else {
        float v[32];
        {
            const float4* Vp = (const float4*)(Vg + b * 1024 + c * 32);
#pragma unroll
            for (int j4 = 0; j4 < 8; ++j4) {
                float4 t = Vp[j4];
                v[4*j4] = t.x; v[4*j4+1] = t.y; v[4*j4+2] = t.z; v[4*j4+3] = t.w;
            }
        }
#pragma unroll
        for (int i = 0; i < 16; ++i) {
            const float4* Mr = (const float4*)&s0[(16 * h + i) * LD2];
            float s = 0.f;
#pragma unroll
            for (int j4 = 0; j4 < 8; ++j4) {
                float4 q = Mr[j4];
                s = fmaf(q.x, v[4*j4],   s);
                s = fmaf(q.y, v[4*j4+1], s);
                s = fmaf(q.z, v[4*j4+2], s);
                s = fmaf(q.w, v[4*j4+3], s);
            }
            a[i] = fmaf(JIT, v[16 * h + i], s);
        }
    }
    jac1(a, aself, a32, c, 10, 1e-12f);
    float gs2 = 0.f;
#pragma unroll
    for (int i = 0; i < 16; ++i) gs2 = fmaf(a[i], a[i], gs2);
    gs2 += bpf(a32, gs2);
    float l = __builtin_amdgcn_sqrtf(gs2);
    float clipl = fmaxf(l, JIT);
    float ig = __builtin_amdgcn_rcpf(gs2);
    float tg = clipl * ig;                      // G:   clip(lam)/lam^2
    float sh = clipl + JIT;                     // next eigh's vals (same eigvecs)
    float ts = __builtin_amdgcn_sqrtf(sh) * ig; // Gs:  sqrt(clip+JIT)/lam^2
    float ti = __builtin_amdgcn_rsqf(sh) * ig;  // Gis: rsqrt(clip+JIT)/lam^2
    if (Vg) {   // store normalized eigvecs for next iteration's warm start
        float inl = __builtin_amdgcn_rsqf(gs2);
        float4* Vp = (float4*)(Vg + b * 1024 + c * 32 + 16 * h);
        Vp[0] = make_float4(a[0]*inl,  a[1]*inl,  a[2]*inl,  a[3]*inl);
        Vp[1] = make_float4(a[4]*inl,  a[5]*inl,  a[6]*inl,  a[7]*inl);
        Vp[2] = make_float4(a[8]*inl,  a[9]*inl,  a[10]*inl, a[11]*inl);
        Vp[3] = make_float4(a[12]*inl, a[13]*inl, a[14]*inl, a[15]*inl);
    }
    wsync();
    {
        float4* wp = (float4*)&s1[c * LD2 + 16 * h];
        wp[0] = make_float4(a[0],  a[1],  a[2],  a[3]);
        wp[1] = make_float4(a[4],  a[5],  a[6],  a[7]);
        wp[2] = make_float4(a[8],  a[9],  a[10], a[11]);
        wp[3] = make_float4(a[12], a[13], a[14], a[15]);
        if (h == 0) { scg[c] = tg; scs[c] = ts; sci[c] = ti; }
    }
    wsync();
    float gg[16], gsv[16], giv[16];
#pragma unroll
    for (int j = 0; j < 16; ++j) { gg[j] = 0.f; gsv[j] = 0.f; giv[j] = 0.f; }
    for (int k = 0; k < DD; ++k) {
        float wr = s1[k * LD2 + r];
        float cg = wr * scg[k], cs2 = wr * scs[k], ci = wr * sci[k];
        const float4* Wc = (const float4*)&s1[k * LD2 + cb];
        float4 w0 = Wc[0], w1 = Wc[1], w2 = Wc[2], w3 = Wc[3];
        gg[0]+=cg*w0.x; gsv[0]+=cs2*w0.x; giv[0]+=ci*w0.x;
        gg[1]+=cg*w0.y; gsv[1]+=cs2*w0.y; giv[1]+=ci*w0.y;
        gg[2]+=cg*w0.z; gsv[2]+=cs2*w0.z; giv[2]+=ci*w0.z;
        gg[3]+=cg*w0.w; gsv[3]+=cs2*w0.w; giv[3]+=ci*w0.w;
        gg[4]+=cg*w1.x; gsv[4]+=cs2*w1.x; giv[4]+=ci*w1.x;
        gg[5]+=cg*w1.y; gsv[5]+=cs2*w1.y; giv[5]+=ci*w1.y;
        gg[6]+=cg*w1.z; gsv[6]+=cs2*w1.z; giv[6]+=ci*w1.z;
        gg[7]+=cg*w1.w; gsv[7]+=cs2*w1.w; giv[7]+=ci*w1.w;
        gg[8]+=cg*w2.x; gsv[8]+=cs2*w2.x; giv[8]+=ci*w2.x;
        gg[9]+=cg*w2.y; gsv[9]+=cs2*w2.y; giv[9]+=ci*w2.y;
        gg[10]+=cg*w2.z; gsv[10]+=cs2*w2.z; giv[10]+=ci*w2.z;
        gg[11]+=cg*w2.w; gsv[11]+=cs2*w2.w; giv[11]+=ci*w2.w;
        gg[12]+=cg*w3.x; gsv[12]+=cs2*w3.x; giv[12]+=ci*w3.x;
        gg[13]+=cg*w3.y; gsv[13]+=cs2*w3.y; giv[13]+=ci*w3.y;
        gg[14]+=cg*w3.z; gsv[14]+=cs2*w3.z; giv[14]+=ci*w3.z;
        gg[15]+=cg*w3.w; gsv[15]+=cs2*w3.w; giv[15]+=ci*w3.w;
    }
    float4* Gb   = (float4*)(G   + b * 1024 + lane * 16);
    float4* Gsb  = (float4*)(Gs  + b * 1024 + lane * 16);
    float4* Gib  = (float4*)(Gis + b * 1024 + lane * 16);
#pragma unroll
    for (int j4 = 0; j4 < 4; ++j4) {
        Gb[j4]  = make_float4(gg[4*j4],  gg[4*j4+1],  gg[4*j4+2],  gg[4*j4+3]);
        Gsb[j4] = make_float4(gsv[4*j4], gsv[4*j4+1], gsv[4*j4+2], gsv[4*j4+3]);
        Gib[j4] = make_float4(giv[4*j4], giv[4*j4+1], giv[4*j4+2], giv[4*j4+3]);
    }

    // convergence check by last-finishing block
    __threadfence();
    if (lane == 0) {
        int ret = atomicAdd(counter, 1);
        if (ret == BB - 1) {
            float nm = atomicAdd(norm_acc, 0.f);
            if (nm * (1.0f / BB) < TOLF) *done = 1;
            *norm_acc = 0.f;
            *counter = 0;
            __threadfence();
        }
    }
}

__global__ __launch_bounds__(256) void k5_out(const float* __restrict__ G, float* __restrict__ out) {
    int i = blockIdx.x * 256 + threadIdx.x;
    out[i] = G[i];
}

extern "C" void kernel_launch(void* const* d_in, const int* in_sizes, int n_in,
                              void* d_out, int out_size, void* d_ws, size_t ws_size,
                              hipStream_t stream) {
    const float* X = (const float*)d_in[0];
    float* ws = (float*)d_ws;
    float* G     = ws;                        // 65536
    float* Gs    = ws + 65536;                // 65536
    float* Gis   = ws + 2 * 65536;            // 65536
    float* Part  = ws + 3 * 65536;            // 1024 blocks * 1024 = 1048576
    float* norm_acc = ws + 3 * 65536 + 1048576;
    int*   counter  = (int*)(norm_acc + 1);
    int*   done     = (int*)(norm_acc + 2);
    size_t base_floats = (size_t)3 * 65536 + 1048576 + 16;
    // Vg: 64*1024 floats (256 KB) for k31 warm start; Vbuf: 64*512*1024 floats (128 MB) for k2
    float* Vg   = (ws_size >= (base_floats + (size_t)BB * 1024) * sizeof(float))
                  ? (ws + base_floats) : nullptr;
    float* Vbuf = (ws_size >= (base_floats + (size_t)BB * 1024 + (size_t)BB * NN * 1024) * sizeof(float))
                  ? (ws + base_floats + (size_t)BB * 1024) : nullptr;

    k0_zero<<<64, 256, 0, stream>>>(G, done, norm_acc, counter);
    k0_mean<<<512, 256, 0, stream>>>(X, G);
    k1_init<<<64, 64, 0, stream>>>(G, Gs, Gis, Vg);
    for (int it = 0; it < MAXIT; ++it) {
        int it_eff = (Vbuf != nullptr) ? it : 0;
        k2_log_acc<<<1024, 512, 0, stream>>>(X, Gis, Part, done, Vbuf, it_eff);
        k31_update<<<64, 64, 0, stream>>>(G, Gs, Gis, Part, norm_acc, counter, done, Vg);
    }
    k5_out<<<256, 256, 0, stream>>>(G, (float*)d_out);
}

// Round 11
// 4868.877 us; speedup vs baseline: 1.6320x; 1.0068x over previous
//
#include <hip/hip_runtime.h>
#include <math.h>

#define BB 64
#define NN 512
#define DD 32
#define LD2 36           // sA leading dim (pad col 32 holds per-column tk)
#define LDG 32           // sG leading dim (broadcast/bank-r reads only)
#define JIT 1e-5f
#define TOLF 1e-4f
#define MAXIT 10

// lane-pull via LDS permute unit; addr = src_lane<<2
__device__ __forceinline__ float bpf(int addr, float v) {
    return __int_as_float(__builtin_amdgcn_ds_bpermute(addr, __float_as_int(v)));
}

__device__ __forceinline__ void wsync() {
    // wave-level LDS handoff (single-wave or per-wave-buffer use only)
    __asm__ volatile("s_waitcnt lgkmcnt(0)" ::: "memory");
}

// ---------------- one-sided (Hestenes) Jacobi, register-resident ----------------
__device__ __forceinline__ void jac1(float a[16], int aself, int a32, int c,
                                     int maxsweep, float thr) {
#pragma unroll 1
    for (int sweep = 0; sweep < maxsweep; ++sweep) {
        float maxrel = 0.f;
#pragma unroll 1
        for (int m = 1; m < 32; ++m) {
            int am = aself ^ (m << 2);
            float pa[16];
#pragma unroll
            for (int i = 0; i < 16; ++i) pa[i] = bpf(am, a[i]);
            float gs = 0.f, gc = 0.f;
#pragma unroll
            for (int i = 0; i < 16; ++i) {
                gs = fmaf(a[i], a[i], gs);
                gc = fmaf(a[i], pa[i], gc);
            }
            gs += bpf(a32, gs);
            gc += bpf(a32, gc);
            float gp = bpf(am, gs);
            bool isP = c < (c ^ m);
            float gpp = isP ? gs : gp;
            float gqq = isP ? gp : gs;
            float rel = gc * gc * __builtin_amdgcn_rcpf(gpp * gqq);
            maxrel = fmaxf(maxrel, rel);
            float tau = (gqq - gpp) * (0.5f * __builtin_amdgcn_rcpf(gc));
            float den = fabsf(tau) + __builtin_amdgcn_sqrtf(fmaf(tau, tau, 1.f));
            float tt  = copysignf(__builtin_amdgcn_rcpf(den), tau);
            tt = (rel > 1e-24f) ? tt : 0.f;
            float cs  = __builtin_amdgcn_rsqf(fmaf(tt, tt, 1.f));
            float sn  = tt * cs;
            float sg = isP ? -sn : sn;
#pragma unroll
            for (int i = 0; i < 16; ++i) a[i] = fmaf(sg, pa[i], cs * a[i]);
        }
#pragma unroll
        for (int sh = 1; sh <= 32; sh <<= 1)
            maxrel = fmaxf(maxrel, bpf(aself ^ (sh << 2), maxrel));
        if (maxrel < thr) break;
    }
}

// C = A * B (32x32, both stride LD2). Wave-synchronous, in-place safe (single wave).
__device__ __forceinline__ void mm32w(const float* A, const float* B, float* C, int lane) {
    int r = lane >> 1, cb = (lane & 1) << 4;
    float acc[16];
#pragma unroll
    for (int j = 0; j < 16; ++j) acc[j] = 0.0f;
    for (int k = 0; k < DD; ++k) {
        float a = A[r * LD2 + k];
        const float4* Br = (const float4*)(B + k * LD2 + cb);
        float4 b0 = Br[0], b1 = Br[1], b2 = Br[2], b3 = Br[3];
        acc[0]  = fmaf(a, b0.x, acc[0]);  acc[1]  = fmaf(a, b0.y, acc[1]);
        acc[2]  = fmaf(a, b0.z, acc[2]);  acc[3]  = fmaf(a, b0.w, acc[3]);
        acc[4]  = fmaf(a, b1.x, acc[4]);  acc[5]  = fmaf(a, b1.y, acc[5]);
        acc[6]  = fmaf(a, b1.z, acc[6]);  acc[7]  = fmaf(a, b1.w, acc[7]);
        acc[8]  = fmaf(a, b2.x, acc[8]);  acc[9]  = fmaf(a, b2.y, acc[9]);
        acc[10] = fmaf(a, b2.z, acc[10]); acc[11] = fmaf(a, b2.w, acc[11]);
        acc[12] = fmaf(a, b3.x, acc[12]); acc[13] = fmaf(a, b3.y, acc[13]);
        acc[14] = fmaf(a, b3.z, acc[14]); acc[15] = fmaf(a, b3.w, acc[15]);
    }
    wsync();
    float4* Cr = (float4*)(C + r * LD2 + cb);
    Cr[0] = make_float4(acc[0],  acc[1],  acc[2],  acc[3]);
    Cr[1] = make_float4(acc[4],  acc[5],  acc[6],  acc[7]);
    Cr[2] = make_float4(acc[8],  acc[9],  acc[10], acc[11]);
    Cr[3] = make_float4(acc[12], acc[13], acc[14], acc[15]);
    wsync();
}

// ---------------- setup ----------------

__global__ __launch_bounds__(256) void k0_zero(float* __restrict__ G, int* __restrict__ done,
                                               float* __restrict__ norm_acc, int* __restrict__ cnt_all,
                                               int* __restrict__ cnt_b) {
    float4* Gb = (float4*)(G + blockIdx.x * 1024);
    Gb[threadIdx.x] = make_float4(0.f, 0.f, 0.f, 0.f);
    if (blockIdx.x == 0) {
        if (threadIdx.x == 0) { *done = 0; *norm_acc = 0.f; *cnt_all = 0; }
        if (threadIdx.x < BB) cnt_b[threadIdx.x] = 0;
    }
}

__global__ __launch_bounds__(256) void k0_mean(const float* __restrict__ X, float* __restrict__ G) {
    int blk = blockIdx.x;
    int b = blk >> 3, chunk = blk & 7;
    int t = threadIdx.x;
    const float4* Xb = (const float4*)(X + ((size_t)(b * NN + chunk * 64)) * 1024);
    float4 acc = make_float4(0.f, 0.f, 0.f, 0.f);
    for (int n = 0; n < 64; ++n) {
        float4 v = Xb[n * 256 + t];
        acc.x += v.x; acc.y += v.y; acc.z += v.z; acc.w += v.w;
    }
    const float inv = 1.0f / NN;
    float* Gb = G + b * 1024 + t * 4;
    atomicAdd(Gb + 0, acc.x * inv);
    atomicAdd(Gb + 1, acc.y * inv);
    atomicAdd(Gb + 2, acc.z * inv);
    atomicAdd(Gb + 3, acc.w * inv);
}

// ---------------- k1: initial eigh(G0) -> Gs, Gis; seed Vg (once) ----------------

__global__ __launch_bounds__(64) void k1_init(const float* __restrict__ G,
                                              float* __restrict__ Gs, float* __restrict__ Gis,
                                              float* __restrict__ Vg) {
    int b = blockIdx.x, lane = threadIdx.x;
    int c = lane & 31, h = lane >> 5;
    int aself = lane << 2, a32 = aself ^ 128;
    int r = lane >> 1, cb = (lane & 1) << 4;
    __shared__ __align__(16) float sW[DD * LD2];
    __shared__ float sc1[DD], sc2[DD];

    float a[16];
    {
        const float4* Gc = (const float4*)(G + b * 1024 + c * 32 + 16 * h);
        float4 v0 = Gc[0], v1 = Gc[1], v2 = Gc[2], v3 = Gc[3];
        a[0]=v0.x; a[1]=v0.y; a[2]=v0.z; a[3]=v0.w;
        a[4]=v1.x; a[5]=v1.y; a[6]=v1.z; a[7]=v1.w;
        a[8]=v2.x; a[9]=v2.y; a[10]=v2.z; a[11]=v2.w;
        a[12]=v3.x; a[13]=v3.y; a[14]=v3.z; a[15]=v3.w;
#pragma unroll
        for (int i = 0; i < 16; ++i)
            if (16 * h + i == c) a[i] += JIT;   // _safe_eigh jitter
    }
    jac1(a, aself, a32, c, 10, 1e-12f);
    float gs2 = 0.f;
#pragma unroll
    for (int i = 0; i < 16; ++i) gs2 = fmaf(a[i], a[i], gs2);
    gs2 += bpf(a32, gs2);
    float l  = __builtin_amdgcn_sqrtf(gs2);
    float lc = fmaxf(l, JIT);
    float ig = __builtin_amdgcn_rcpf(gs2);
    float c1 = __builtin_amdgcn_sqrtf(lc) * ig;   // sqrt(clip(lam)) / lam^2
    float c2 = __builtin_amdgcn_rsqf(lc) * ig;    // 1/sqrt(clip(lam)) / lam^2
    if (Vg) {   // seed warm-start basis for the fused epilogue
        float inl = __builtin_amdgcn_rsqf(gs2);
        float4* Vp = (float4*)(Vg + b * 1024 + c * 32 + 16 * h);
        Vp[0] = make_float4(a[0]*inl,  a[1]*inl,  a[2]*inl,  a[3]*inl);
        Vp[1] = make_float4(a[4]*inl,  a[5]*inl,  a[6]*inl,  a[7]*inl);
        Vp[2] = make_float4(a[8]*inl,  a[9]*inl,  a[10]*inl, a[11]*inl);
        Vp[3] = make_float4(a[12]*inl, a[13]*inl, a[14]*inl, a[15]*inl);
    }
    {
        float4* wp = (float4*)&sW[c * LD2 + 16 * h];
        wp[0] = make_float4(a[0],  a[1],  a[2],  a[3]);
        wp[1] = make_float4(a[4],  a[5],  a[6],  a[7]);
        wp[2] = make_float4(a[8],  a[9],  a[10], a[11]);
        wp[3] = make_float4(a[12], a[13], a[14], a[15]);
        if (h == 0) { sc1[c] = c1; sc2[c] = c2; }
    }
    wsync();
    float a1[16], a2[16];
#pragma unroll
    for (int j = 0; j < 16; ++j) { a1[j] = 0.f; a2[j] = 0.f; }
    for (int k = 0; k < DD; ++k) {
        float wr = sW[k * LD2 + r];
        float t1 = wr * sc1[k], t2 = wr * sc2[k];
        const float4* Wc = (const float4*)&sW[k * LD2 + cb];
        float4 w0 = Wc[0], w1 = Wc[1], w2 = Wc[2], w3 = Wc[3];
        a1[0]+=t1*w0.x; a2[0]+=t2*w0.x;  a1[1]+=t1*w0.y; a2[1]+=t2*w0.y;
        a1[2]+=t1*w0.z; a2[2]+=t2*w0.z;  a1[3]+=t1*w0.w; a2[3]+=t2*w0.w;
        a1[4]+=t1*w1.x; a2[4]+=t2*w1.x;  a1[5]+=t1*w1.y; a2[5]+=t2*w1.y;
        a1[6]+=t1*w1.z; a2[6]+=t2*w1.z;  a1[7]+=t1*w1.w; a2[7]+=t2*w1.w;
        a1[8]+=t1*w2.x; a2[8]+=t2*w2.x;  a1[9]+=t1*w2.y; a2[9]+=t2*w2.y;
        a1[10]+=t1*w2.z; a2[10]+=t2*w2.z; a1[11]+=t1*w2.w; a2[11]+=t2*w2.w;
        a1[12]+=t1*w3.x; a2[12]+=t2*w3.x; a1[13]+=t1*w3.y; a2[13]+=t2*w3.y;
        a1[14]+=t1*w3.z; a2[14]+=t2*w3.z; a1[15]+=t1*w3.w; a2[15]+=t2*w3.w;
    }
    float4* Gsb  = (float4*)(Gs  + b * 1024 + lane * 16);
    float4* Gisb = (float4*)(Gis + b * 1024 + lane * 16);
#pragma unroll
    for (int j4 = 0; j4 < 4; ++j4) {
        Gsb[j4]  = make_float4(a1[4*j4], a1[4*j4+1], a1[4*j4+2], a1[4*j4+3]);
        Gisb[j4] = make_float4(a2[4*j4], a2[4*j4+1], a2[4*j4+2], a2[4*j4+3]);
    }
}

// ---------------- k2: hot kernel + fused per-b epilogue (ex-k31) ----------------
// 1024 blocks x 8 waves; wave handles 4 matrices. The last-finishing of a batch's
// 16 blocks runs the G-update epilogue (Delta mean/norm, expm, Gs E Gs,
// enforce_spd eigh warm-started from Vg) on its wave 0.
// __launch_bounds__(512, 6): pin 6 waves/EU -> VGPR <= 85, matching LDS limit.

__global__ __launch_bounds__(512, 6) void k2_log_acc(const float* __restrict__ X,
                                                     float* G, float* Gs, float* Gis,
                                                     float* __restrict__ Part,
                                                     int* __restrict__ done,
                                                     float* __restrict__ Vbuf,
                                                     float* __restrict__ Vg,
                                                     float* __restrict__ norm_acc,
                                                     int* __restrict__ cnt_all,
                                                     int* __restrict__ cnt_b,
                                                     int it) {
    if (*done) return;
    int b = blockIdx.x >> 4, grp = blockIdx.x & 15;
    int wv = threadIdx.x >> 6, lane = threadIdx.x & 63;
    int c = lane & 31, h = lane >> 5;
    int aself = lane << 2, a32 = aself ^ 128;

    __shared__ __align__(16) float sG[DD * LDG];           // 4096 B
    __shared__ __align__(16) float sAall[8][DD * LD2];     // 36864 B
    float* sA = sAall[wv];

    if (threadIdx.x < 256)
        ((float4*)sG)[threadIdx.x] = ((const float4*)(Gis + b * 1024))[threadIdx.x];
    __syncthreads();

    int r = lane >> 1, cb = (lane & 1) << 4;
    float dacc[16];
#pragma unroll
    for (int j = 0; j < 16; ++j) dacc[j] = 0.f;

#pragma unroll 1
    for (int nn = 0; nn < 4; ++nn) {
        int n = grp * 32 + wv * 4 + nn;
        // ---- stage X[b,n] -> sA ----
        {
            const float4* Xv = (const float4*)(X + ((size_t)(b * NN + n)) * 1024);
            float4 v0 = Xv[lane * 4 + 0], v1 = Xv[lane * 4 + 1];
            float4 v2 = Xv[lane * 4 + 2], v3 = Xv[lane * 4 + 3];
            wsync();   // all prior readers of sA done
            int e = lane * 16;
            float* d0 = &sA[(e >> 5) * LD2 + (e & 31)];
            *((float4*)d0)        = v0;
            *((float4*)(d0 + 4))  = v1;
            *((float4*)(d0 + 8))  = v2;
            *((float4*)(d0 + 12)) = v3;
            wsync();
        }
        // ---- T = Gis * X (A-operand transposed read from sG: conflict-free) ----
        {
            float acc[16];
#pragma unroll
            for (int j = 0; j < 16; ++j) acc[j] = 0.f;
            for (int k = 0; k < DD; ++k) {
                float a = sG[k * LDG + r];
                const float4* Br = (const float4*)(sA + k * LD2 + cb);
                float4 b0 = Br[0], b1 = Br[1], b2 = Br[2], b3 = Br[3];
                acc[0]  = fmaf(a, b0.x, acc[0]);  acc[1]  = fmaf(a, b0.y, acc[1]);
                acc[2]  = fmaf(a, b0.z, acc[2]);  acc[3]  = fmaf(a, b0.w, acc[3]);
                acc[4]  = fmaf(a, b1.x, acc[4]);  acc[5]  = fmaf(a, b1.y, acc[5]);
                acc[6]  = fmaf(a, b1.z, acc[6]);  acc[7]  = fmaf(a, b1.w, acc[7]);
                acc[8]  = fmaf(a, b2.x, acc[8]);  acc[9]  = fmaf(a, b2.y, acc[9]);
                acc[10] = fmaf(a, b2.z, acc[10]); acc[11] = fmaf(a, b2.w, acc[11]);
                acc[12] = fmaf(a, b3.x, acc[12]); acc[13] = fmaf(a, b3.y, acc[13]);
                acc[14] = fmaf(a, b3.z, acc[14]); acc[15] = fmaf(a, b3.w, acc[15]);
            }
            wsync();
            float4* Cr = (float4*)(sA + r * LD2 + cb);
            Cr[0] = make_float4(acc[0],  acc[1],  acc[2],  acc[3]);
            Cr[1] = make_float4(acc[4],  acc[5],  acc[6],  acc[7]);
            Cr[2] = make_float4(acc[8],  acc[9],  acc[10], acc[11]);
            Cr[3] = make_float4(acc[12], acc[13], acc[14], acc[15]);
            wsync();
        }
        // ---- A = T * Gis ----
        {
            float acc[16];
#pragma unroll
            for (int j = 0; j < 16; ++j) acc[j] = 0.f;
            for (int k = 0; k < DD; ++k) {
                float a = sA[r * LD2 + k];
                const float4* Br = (const float4*)(sG + k * LDG + cb);
                float4 b0 = Br[0], b1 = Br[1], b2 = Br[2], b3 = Br[3];
                acc[0]  = fmaf(a, b0.x, acc[0]);  acc[1]  = fmaf(a, b0.y, acc[1]);
                acc[2]  = fmaf(a, b0.z, acc[2]);  acc[3]  = fmaf(a, b0.w, acc[3]);
                acc[4]  = fmaf(a, b1.x, acc[4]);  acc[5]  = fmaf(a, b1.y, acc[5]);
                acc[6]  = fmaf(a, b1.z, acc[6]);  acc[7]  = fmaf(a, b1.w, acc[7]);
                acc[8]  = fmaf(a, b2.x, acc[8]);  acc[9]  = fmaf(a, b2.y, acc[9]);
                acc[10] = fmaf(a, b2.z, acc[10]); acc[11] = fmaf(a, b2.w, acc[11]);
                acc[12] = fmaf(a, b3.x, acc[12]); acc[13] = fmaf(a, b3.y, acc[13]);
                acc[14] = fmaf(a, b3.z, acc[14]); acc[15] = fmaf(a, b3.w, acc[15]);
            }
            wsync();
            float4* Cr = (float4*)(sA + r * LD2 + cb);
            Cr[0] = make_float4(acc[0],  acc[1],  acc[2],  acc[3]);
            Cr[1] = make_float4(acc[4],  acc[5],  acc[6],  acc[7]);
            Cr[2] = make_float4(acc[8],  acc[9],  acc[10], acc[11]);
            Cr[3] = make_float4(acc[12], acc[13], acc[14], acc[15]);
            wsync();
        }
        // ---- initial W columns: cold (A cols, symmetrized) or warm (A * V_prev) ----
        float a[16];
        if (it == 0) {
            const float4* cp = (const float4*)&sA[c * LD2 + 16 * h];
            float4 t0 = cp[0], t1 = cp[1], t2 = cp[2], t3 = cp[3];
            float tr[16] = { t0.x,t0.y,t0.z,t0.w, t1.x,t1.y,t1.z,t1.w,
                             t2.x,t2.y,t2.z,t2.w, t3.x,t3.y,t3.z,t3.w };
#pragma unroll
            for (int i = 0; i < 16; ++i) {
                int row = 16 * h + i;
                float v = 0.5f * (sA[row * LD2 + c] + tr[i]);
                if (row == c) v = tr[i] + JIT;
                a[i] = v;
            }
        } else {
            // w_c = (A + JIT I) * vhat_prev_c ; vhat in registers, A rows broadcast from LDS
            float v[32];
            {
                const float4* Vp = (const float4*)(Vbuf + ((size_t)(b * NN + n)) * 1024 + c * 32);
#pragma unroll
                for (int j4 = 0; j4 < 8; ++j4) {
                    float4 t = Vp[j4];
                    v[4*j4] = t.x; v[4*j4+1] = t.y; v[4*j4+2] = t.z; v[4*j4+3] = t.w;
                }
            }
#pragma unroll
            for (int i = 0; i < 16; ++i) {
                const float4* Ar = (const float4*)&sA[(16 * h + i) * LD2];
                float s = 0.f;
#pragma unroll
                for (int j4 = 0; j4 < 8; ++j4) {
                    float4 q = Ar[j4];
                    s = fmaf(q.x, v[4*j4],   s);
                    s = fmaf(q.y, v[4*j4+1], s);
                    s = fmaf(q.z, v[4*j4+2], s);
                    s = fmaf(q.w, v[4*j4+3], s);
                }
                a[i] = fmaf(JIT, v[16 * h + i], s);
            }
        }

        jac1(a, aself, a32, c, 8, 1e-8f);

        // ---- eigen extraction + V store + rebuild ----
        {
            float gs2 = 0.f;
#pragma unroll
            for (int i = 0; i < 16; ++i) gs2 = fmaf(a[i], a[i], gs2);
            gs2 += bpf(a32, gs2);
            float gs2c = fmaxf(gs2, JIT * JIT);
            float tk = 0.5f * logf(gs2c) * __builtin_amdgcn_rcpf(gs2);
            if (Vbuf) {   // store normalized eigenvectors for next iteration's warm start
                float inl = __builtin_amdgcn_rsqf(gs2);
                float4* Vp = (float4*)(Vbuf + ((size_t)(b * NN + n)) * 1024 + c * 32 + 16 * h);
                Vp[0] = make_float4(a[0]*inl,  a[1]*inl,  a[2]*inl,  a[3]*inl);
                Vp[1] = make_float4(a[4]*inl,  a[5]*inl,  a[6]*inl,  a[7]*inl);
                Vp[2] = make_float4(a[8]*inl,  a[9]*inl,  a[10]*inl, a[11]*inl);
                Vp[3] = make_float4(a[12]*inl, a[13]*inl, a[14]*inl, a[15]*inl);
            }
            wsync();   // prior readers of sA done
            float4* wp = (float4*)&sA[c * LD2 + 16 * h];
            wp[0] = make_float4(a[0],  a[1],  a[2],  a[3]);
            wp[1] = make_float4(a[4],  a[5],  a[6],  a[7]);
            wp[2] = make_float4(a[8],  a[9],  a[10], a[11]);
            wp[3] = make_float4(a[12], a[13], a[14], a[15]);
            if (h == 0) sA[c * LD2 + 32] = tk;          // tk in row padding
            wsync();
            for (int k = 0; k < DD; ++k) {
                float t1 = sA[k * LD2 + r] * sA[k * LD2 + 32];
                const float4* Wr = (const float4*)&sA[k * LD2 + cb];
                float4 w0 = Wr[0], w1 = Wr[1], w2 = Wr[2], w3 = Wr[3];
                dacc[0]  = fmaf(t1, w0.x, dacc[0]);  dacc[1]  = fmaf(t1, w0.y, dacc[1]);
                dacc[2]  = fmaf(t1, w0.z, dacc[2]);  dacc[3]  = fmaf(t1, w0.w, dacc[3]);
                dacc[4]  = fmaf(t1, w1.x, dacc[4]);  dacc[5]  = fmaf(t1, w1.y, dacc[5]);
                dacc[6]  = fmaf(t1, w1.z, dacc[6]);  dacc[7]  = fmaf(t1, w1.w, dacc[7]);
                dacc[8]  = fmaf(t1, w2.x, dacc[8]);  dacc[9]  = fmaf(t1, w2.y, dacc[9]);
                dacc[10] = fmaf(t1, w2.z, dacc[10]); dacc[11] = fmaf(t1, w2.w, dacc[11]);
                dacc[12] = fmaf(t1, w3.x, dacc[12]); dacc[13] = fmaf(t1, w3.y, dacc[13]);
                dacc[14] = fmaf(t1, w3.z, dacc[14]); dacc[15] = fmaf(t1, w3.w, dacc[15]);
            }
        }
    }
    wsync();

    // ---- block reduction -> Part ----
    {
        float4* fp = (float4*)&sA[lane * 16];
        fp[0] = make_float4(dacc[0],  dacc[1],  dacc[2],  dacc[3]);
        fp[1] = make_float4(dacc[4],  dacc[5],  dacc[6],  dacc[7]);
        fp[2] = make_float4(dacc[8],  dacc[9],  dacc[10], dacc[11]);
        fp[3] = make_float4(dacc[12], dacc[13], dacc[14], dacc[15]);
    }
    __syncthreads();
    if (threadIdx.x < 256) {
        int t = threadIdx.x;
        float4 s0 = ((float4*)sAall[0])[t];
        float4 s1 = ((float4*)sAall[1])[t];
        float4 s2 = ((float4*)sAall[2])[t];
        float4 s3 = ((float4*)sAall[3])[t];
        float4 s4 = ((float4*)sAall[4])[t];
        float4 s5 = ((float4*)sAall[5])[t];
        float4 s6 = ((float4*)sAall[6])[t];
        float4 s7 = ((float4*)sAall[7])[t];
        float4 s;
        s.x = ((s0.x + s1.x) + (s2.x + s3.x)) + ((s4.x + s5.x) + (s6.x + s7.x));
        s.y = ((s0.y + s1.y) + (s2.y + s3.y)) + ((s4.y + s5.y) + (s6.y + s7.y));
        s.z = ((s0.z + s1.z) + (s2.z + s3.z)) + ((s4.z + s5.z) + (s6.z + s7.z));
        s.w = ((s0.w + s1.w) + (s2.w + s3.w)) + ((s4.w + s5.w) + (s6.w + s7.w));
        ((float4*)(Part + (size_t)blockIdx.x * 1024))[t] = s;
    }

    // ---- elect last-finishing block of this b ----
    int* winp = (int*)sG;   // sG dead now; reuse 4 bytes
    if (threadIdx.x == 0) *winp = 0;
    __syncthreads();        // Part stores complete (intra-block) + winp init
    if (threadIdx.x == 0) {
        __threadfence();    // release: our Part visible before count
        int ret = atomicAdd(&cnt_b[b], 1);
        if (ret == 15) { *winp = 1; cnt_b[b] = 0; }
    }
    __syncthreads();
    if (*winp == 0) return;
    if (threadIdx.x >= 64) return;
    __threadfence();        // acquire: other blocks' Part now visible

    // ==== fused epilogue (ex-k31), wave 0 only ====
    {
        float* s0 = sAall[0];
        float* s1 = sAall[1];
        float* s2 = sAall[2];
        float* scof = sAall[3];   // [0..31] G, [32..63] Gs, [64..95] Gis coefficients

        // Delta = sum of 16 partials / NN
        float d[16];
#pragma unroll
        for (int j = 0; j < 16; ++j) d[j] = 0.f;
#pragma unroll 1
        for (int g = 0; g < 16; ++g) {
            const float4* P = (const float4*)(Part + (size_t)(b * 16 + g) * 1024 + lane * 16);
            float4 p0 = P[0], p1 = P[1], p2 = P[2], p3 = P[3];
            d[0]+=p0.x; d[1]+=p0.y; d[2]+=p0.z; d[3]+=p0.w;
            d[4]+=p1.x; d[5]+=p1.y; d[6]+=p1.z; d[7]+=p1.w;
            d[8]+=p2.x; d[9]+=p2.y; d[10]+=p2.z; d[11]+=p2.w;
            d[12]+=p3.x; d[13]+=p3.y; d[14]+=p3.z; d[15]+=p3.w;
        }
        const float inv = 1.0f / NN;
        float sumsq = 0.f;
#pragma unroll
        for (int j = 0; j < 16; ++j) { d[j] *= inv; sumsq = fmaf(d[j], d[j], sumsq); }
#pragma unroll
        for (int sh = 1; sh <= 32; sh <<= 1) sumsq += bpf(aself ^ (sh << 2), sumsq);
        if (lane == 0) atomicAdd(norm_acc, sqrtf(sumsq));

        wsync();   // all waves' reduction reads of sAall are done (post-barrier); safe to overwrite
        // Delta -> s0
        {
            float4* dp = (float4*)&s0[r * LD2 + cb];
            dp[0] = make_float4(d[0],  d[1],  d[2],  d[3]);
            dp[1] = make_float4(d[4],  d[5],  d[6],  d[7]);
            dp[2] = make_float4(d[8],  d[9],  d[10], d[11]);
            dp[3] = make_float4(d[12], d[13], d[14], d[15]);
        }
        wsync();

        // expm_taylor order 5
        float outr[16];
#pragma unroll
        for (int j = 0; j < 16; ++j)
            outr[j] = ((cb + j) == r ? 1.0f : 0.0f) + d[j];
        float fac = 1.0f;
#pragma unroll 1
        for (int i = 2; i <= 5; ++i) {
            fac *= (float)i;
            float acc[16];
#pragma unroll
            for (int j = 0; j < 16; ++j) acc[j] = 0.f;
            const float* Xp = (i == 2) ? s0 : s1;
            for (int k = 0; k < DD; ++k) {
                float av = Xp[r * LD2 + k];
                const float4* Br = (const float4*)&s0[k * LD2 + cb];
                float4 b0 = Br[0], b1 = Br[1], b2 = Br[2], b3 = Br[3];
                acc[0]+=av*b0.x; acc[1]+=av*b0.y; acc[2]+=av*b0.z; acc[3]+=av*b0.w;
                acc[4]+=av*b1.x; acc[5]+=av*b1.y; acc[6]+=av*b1.z; acc[7]+=av*b1.w;
                acc[8]+=av*b2.x; acc[9]+=av*b2.y; acc[10]+=av*b2.z; acc[11]+=av*b2.w;
                acc[12]+=av*b3.x; acc[13]+=av*b3.y; acc[14]+=av*b3.z; acc[15]+=av*b3.w;
            }
            float invf = 1.0f / fac;
#pragma unroll
            for (int j = 0; j < 16; ++j) outr[j] = fmaf(acc[j], invf, outr[j]);
            wsync();
            float4* dp = (float4*)&s1[r * LD2 + cb];
            dp[0] = make_float4(acc[0],  acc[1],  acc[2],  acc[3]);
            dp[1] = make_float4(acc[4],  acc[5],  acc[6],  acc[7]);
            dp[2] = make_float4(acc[8],  acc[9],  acc[10], acc[11]);
            dp[3] = make_float4(acc[12], acc[13], acc[14], acc[15]);
            wsync();
        }
        // E -> s0; Gs_old -> s1
        {
            float4* dp = (float4*)&s0[r * LD2 + cb];
            dp[0] = make_float4(outr[0],  outr[1],  outr[2],  outr[3]);
            dp[1] = make_float4(outr[4],  outr[5],  outr[6],  outr[7]);
            dp[2] = make_float4(outr[8],  outr[9],  outr[10], outr[11]);
            dp[3] = make_float4(outr[12], outr[13], outr[14], outr[15]);
            const float4* Gsb = (const float4*)(Gs + b * 1024);
#pragma unroll
            for (int j4 = 0; j4 < 4; ++j4) {
                float4 v = Gsb[lane * 4 + j4];
                int e = lane * 16 + j4 * 4;
                *((float4*)&s1[(e >> 5) * LD2 + (e & 31)]) = v;
            }
        }
        wsync();
        mm32w(s1, s0, s2, lane);   // T = Gs * E
        mm32w(s2, s1, s0, lane);   // M = T * Gs

        // enforce_spd eigh: cold (symmetrized cols) or warm (M * Vg + JIT Vg)
        float a[16];
        if (Vg == nullptr) {
#pragma unroll
            for (int i = 0; i < 16; ++i) {
                int row = 16 * h + i;
                float own = s0[c * LD2 + row];
                float v = 0.5f * (s0[row * LD2 + c] + own);
                if (row == c) v = own + JIT;
                a[i] = v;
            }
        } else {
            float v[32];
            {
                const float4* Vp = (const float4*)(Vg + b * 1024 + c * 32);
#pragma unroll
                for (int j4 = 0; j4 < 8; ++j4) {
                    float4 t = Vp[j4];
                    v[4*j4] = t.x; v[4*j4+1] = t.y; v[4*j4+2] = t.z; v[4*j4+3] = t.w;
                }
            }
#pragma unroll
            for (int i = 0; i < 16; ++i) {
                const float4* Mr = (const float4*)&s0[(16 * h + i) * LD2];
                float s = 0.f;
#pragma unroll
                for (int j4 = 0; j4 < 8; ++j4) {
                    float4 q = Mr[j4];
                    s = fmaf(q.x, v[4*j4],   s);
                    s = fmaf(q.y, v[4*j4+1], s);
                    s = fmaf(q.z, v[4*j4+2], s);
                    s = fmaf(q.w, v[4*j4+3], s);
                }
                a[i] = fmaf(JIT, v[16 * h + i], s);
            }
        }
        jac1(a, aself, a32, c, 10, 1e-12f);
        float gs2 = 0.f;
#pragma unroll
        for (int i = 0; i < 16; ++i) gs2 = fmaf(a[i], a[i], gs2);
        gs2 += bpf(a32, gs2);
        float l = __builtin_amdgcn_sqrtf(gs2);
        float clipl = fmaxf(l, JIT);
        float ig = __builtin_amdgcn_rcpf(gs2);
        float tg = clipl * ig;                      // G:   clip(lam)/lam^2
        float sh = clipl + JIT;                     // next eigh's vals (same eigvecs)
        float ts = __builtin_amdgcn_sqrtf(sh) * ig; // Gs:  sqrt(clip+JIT)/lam^2
        float ti = __builtin_amdgcn_rsqf(sh) * ig;  // Gis: rsqrt(clip+JIT)/lam^2
        if (Vg) {   // store normalized eigvecs for next iteration's warm start
            float inl = __builtin_amdgcn_rsqf(gs2);
            float4* Vp = (float4*)(Vg + b * 1024 + c * 32 + 16 * h);
            Vp[0] = make_float4(a[0]*inl,  a[1]*inl,  a[2]*inl,  a[3]*inl);
            Vp[1] = make_float4(a[4]*inl,  a[5]*inl,  a[6]*inl,  a[7]*inl);
            Vp[2] = make_float4(a[8]*inl,  a[9]*inl,  a[10]*inl, a[11]*inl);
            Vp[3] = make_float4(a[12]*inl, a[13]*inl, a[14]*inl, a[15]*inl);
        }
        wsync();
        // W -> s1, coeffs -> scof
        {
            float4* wp = (float4*)&s1[c * LD2 + 16 * h];
            wp[0] = make_float4(a[0],  a[1],  a[2],  a[3]);
            wp[1] = make_float4(a[4],  a[5],  a[6],  a[7]);
            wp[2] = make_float4(a[8],  a[9],  a[10], a[11]);
            wp[3] = make_float4(a[12], a[13], a[14], a[15]);
            if (h == 0) { scof[c] = tg; scof[32 + c] = ts; scof[64 + c] = ti; }
        }
        wsync();
        // three low-register passes: G, Gs, Gis = W diag(coef) W^T
#pragma unroll 1
        for (int pass = 0; pass < 3; ++pass) {
            float g[16];
#pragma unroll
            for (int j = 0; j < 16; ++j) g[j] = 0.f;
            for (int k = 0; k < DD; ++k) {
                float t1 = s1[k * LD2 + r] * scof[pass * 32 + k];
                const float4* Wc = (const float4*)&s1[k * LD2 + cb];
                float4 w0 = Wc[0], w1 = Wc[1], w2 = Wc[2], w3 = Wc[3];
                g[0]+=t1*w0.x; g[1]+=t1*w0.y; g[2]+=t1*w0.z; g[3]+=t1*w0.w;
                g[4]+=t1*w1.x; g[5]+=t1*w1.y; g[6]+=t1*w1.z; g[7]+=t1*w1.w;
                g[8]+=t1*w2.x; g[9]+=t1*w2.y; g[10]+=t1*w2.z; g[11]+=t1*w2.w;
                g[12]+=t1*w3.x; g[13]+=t1*w3.y; g[14]+=t1*w3.z; g[15]+=t1*w3.w;
            }
            float* dst = (pass == 0) ? G : (pass == 1) ? Gs : Gis;
            float4* Db = (float4*)(dst + b * 1024 + lane * 16);
#pragma unroll
            for (int j4 = 0; j4 < 4; ++j4)
                Db[j4] = make_float4(g[4*j4], g[4*j4+1], g[4*j4+2], g[4*j4+3]);
        }

        // global convergence check by last-finishing batch
        __threadfence();
        if (lane == 0) {
            int r2 = atomicAdd(cnt_all, 1);
            if (r2 == BB - 1) {
                float nm = atomicAdd(norm_acc, 0.f);
                if (nm * (1.0f / BB) < TOLF) *done = 1;
                *norm_acc = 0.f;
                *cnt_all = 0;
                __threadfence();
            }
        }
    }
}

__global__ __launch_bounds__(256) void k5_out(const float* __restrict__ G, float* __restrict__ out) {
    int i = blockIdx.x * 256 + threadIdx.x;
    out[i] = G[i];
}

extern "C" void kernel_launch(void* const* d_in, const int* in_sizes, int n_in,
                              void* d_out, int out_size, void* d_ws, size_t ws_size,
                              hipStream_t stream) {
    const float* X = (const float*)d_in[0];
    float* ws = (float*)d_ws;
    float* G     = ws;                        // 65536
    float* Gs    = ws + 65536;                // 65536
    float* Gis   = ws + 2 * 65536;            // 65536
    float* Part  = ws + 3 * 65536;            // 1024 blocks * 1024 = 1048576
    float* norm_acc = ws + 3 * 65536 + 1048576;
    int*   cnt_all  = (int*)(norm_acc + 1);
    int*   done     = (int*)(norm_acc + 2);
    int*   cnt_b    = (int*)(norm_acc + 3);   // 64 ints
    size_t base_floats = (size_t)3 * 65536 + 1048576 + 80;  // aligned past counters
    // Vg: 64*1024 floats (256 KB) epilogue warm start; Vbuf: 64*512*1024 floats (128 MB) k2 warm start
    float* Vg   = (ws_size >= (base_floats + (size_t)BB * 1024) * sizeof(float))
                  ? (ws + base_floats) : nullptr;
    float* Vbuf = (ws_size >= (base_floats + (size_t)BB * 1024 + (size_t)BB * NN * 1024) * sizeof(float))
                  ? (ws + base_floats + (size_t)BB * 1024) : nullptr;

    k0_zero<<<64, 256, 0, stream>>>(G, done, norm_acc, cnt_all, cnt_b);
    k0_mean<<<512, 256, 0, stream>>>(X, G);
    k1_init<<<64, 64, 0, stream>>>(G, Gs, Gis, Vg);
    for (int it = 0; it < MAXIT; ++it) {
        int it_eff = (Vbuf != nullptr) ? it : 0;
        k2_log_acc<<<1024, 512, 0, stream>>>(X, G, Gs, Gis, Part, done, Vbuf, Vg,
                                             norm_acc, cnt_all, cnt_b, it_eff);
    }
    k5_out<<<256, 256, 0, stream>>>(G, (float*)d_out);
}